// Round 1
// baseline (6589.264 us; speedup 1.0000x reference)
//
#include <hip/hip_runtime.h>
#include <math.h>

#define NB 16
#define SEQ 1024
#define DM 512
#define KD 128
#define TEMP_F 30.0f
#define NORM_SCALE_F 0.011048543456039805f  // sqrt(1/8192)

// ---------------- transpose in: src [B][D][S] -> dst [B][S][D] ----------------
__global__ __launch_bounds__(256) void k_transpose_in(const float* __restrict__ src,
                                                      float* __restrict__ dst) {
    __shared__ float tile[32][33];
    const int b = blockIdx.z;
    const int d0 = blockIdx.x * 32;
    const int s0 = blockIdx.y * 32;
    const int tx = threadIdx.x, ty = threadIdx.y;  // 32x8
    const float* p = src + (size_t)b * DM * SEQ;
    float* q = dst + (size_t)b * SEQ * DM;
#pragma unroll
    for (int j = 0; j < 32; j += 8)
        tile[ty + j][tx] = p[(size_t)(d0 + ty + j) * SEQ + s0 + tx];
    __syncthreads();
#pragma unroll
    for (int j = 0; j < 32; j += 8)
        q[(size_t)(s0 + ty + j) * DM + d0 + tx] = tile[tx][ty + j];
}

// ---------------- transpose out: src [B][S][D] -> dst [B][D][S] ----------------
__global__ __launch_bounds__(256) void k_transpose_out(const float* __restrict__ src,
                                                       float* __restrict__ dst) {
    __shared__ float tile[32][33];
    const int b = blockIdx.z;
    const int s0 = blockIdx.x * 32;
    const int d0 = blockIdx.y * 32;
    const int tx = threadIdx.x, ty = threadIdx.y;  // 32x8
    const float* p = src + (size_t)b * SEQ * DM;
    float* q = dst + (size_t)b * DM * SEQ;
#pragma unroll
    for (int j = 0; j < 32; j += 8)
        tile[ty + j][tx] = p[(size_t)(s0 + ty + j) * DM + d0 + tx];
    __syncthreads();
#pragma unroll
    for (int j = 0; j < 32; j += 8)
        q[(size_t)(d0 + ty + j) * SEQ + s0 + tx] = tile[tx][ty + j];
}

// ---------------- projection + l2norm: W[row][k] = normalize(X[row]@WK + bK) ----------------
// 8 rows per block, 128 threads (one k per thread)
__global__ __launch_bounds__(128) void k_proj(const float* __restrict__ Xp,
                                              const float* __restrict__ WK,
                                              const float* __restrict__ bK,
                                              float* __restrict__ Wout) {
    const int row0 = blockIdx.x * 8;
    const int k = threadIdx.x;
    __shared__ float xr[8][DM];
#pragma unroll
    for (int r = 0; r < 8; ++r)
        ((float4*)xr[r])[k] = ((const float4*)(Xp + (size_t)(row0 + r) * DM))[k];
    __syncthreads();
    float acc[8];
    const float bv = bK[k];
#pragma unroll
    for (int r = 0; r < 8; ++r) acc[r] = bv;
    for (int d = 0; d < DM; d += 4) {
        const float w0 = WK[(d + 0) * KD + k];
        const float w1 = WK[(d + 1) * KD + k];
        const float w2 = WK[(d + 2) * KD + k];
        const float w3 = WK[(d + 3) * KD + k];
#pragma unroll
        for (int r = 0; r < 8; ++r) {
            float4 xv = *(const float4*)&xr[r][d];
            acc[r] = fmaf(xv.x, w0, acc[r]);
            acc[r] = fmaf(xv.y, w1, acc[r]);
            acc[r] = fmaf(xv.z, w2, acc[r]);
            acc[r] = fmaf(xv.w, w3, acc[r]);
        }
    }
    __shared__ float part[2][8];
    const int lane = k & 63, wv = k >> 6;
#pragma unroll
    for (int r = 0; r < 8; ++r) {
        float v = acc[r] * acc[r];
#pragma unroll
        for (int o = 32; o > 0; o >>= 1) v += __shfl_xor(v, o, 64);
        if (lane == 0) part[wv][r] = v;
    }
    __syncthreads();
#pragma unroll
    for (int r = 0; r < 8; ++r) {
        float n = sqrtf(part[0][r] + part[1][r]);
        n = fmaxf(n, 1e-12f);
        Wout[(size_t)(row0 + r) * KD + k] = acc[r] / n;
    }
}

// ---------------- QK^T: Aff[bz][i][j] = TEMP * dot(Wq[b][i], Wk[b][j]) ----------------
__global__ __launch_bounds__(256) void k_qk(const float* __restrict__ Wq,
                                            const float* __restrict__ Wk,
                                            float* __restrict__ Aff, int b0) {
    const int bz = blockIdx.z, b = b0 + bz;
    const float* Ab = Wq + (size_t)b * SEQ * KD;
    const float* Bb = Wk + (size_t)b * SEQ * KD;
    float* Cb = Aff + (size_t)bz * SEQ * SEQ;
    const int i0 = blockIdx.y * 64, j0 = blockIdx.x * 64;
    __shared__ float As[64][17], Bs[64][17];
    const int tid = threadIdx.x;
    const int li = tid >> 2, lk = (tid & 3) * 4;
    const int r0 = (tid >> 4) * 4, c0 = (tid & 15) * 4;
    float acc[4][4] = {};
    for (int k0 = 0; k0 < KD; k0 += 16) {
        float4 a4 = *(const float4*)&Ab[(size_t)(i0 + li) * KD + k0 + lk];
        float4 b4 = *(const float4*)&Bb[(size_t)(j0 + li) * KD + k0 + lk];
        As[li][lk] = a4.x; As[li][lk + 1] = a4.y; As[li][lk + 2] = a4.z; As[li][lk + 3] = a4.w;
        Bs[li][lk] = b4.x; Bs[li][lk + 1] = b4.y; Bs[li][lk + 2] = b4.z; Bs[li][lk + 3] = b4.w;
        __syncthreads();
#pragma unroll
        for (int kk = 0; kk < 16; ++kk) {
            float a[4], bb[4];
#pragma unroll
            for (int r = 0; r < 4; ++r) a[r] = As[r0 + r][kk];
#pragma unroll
            for (int c = 0; c < 4; ++c) bb[c] = Bs[c0 + c][kk];
#pragma unroll
            for (int r = 0; r < 4; ++r)
#pragma unroll
                for (int c = 0; c < 4; ++c)
                    acc[r][c] = fmaf(a[r], bb[c], acc[r][c]);
        }
        __syncthreads();
    }
#pragma unroll
    for (int r = 0; r < 4; ++r) {
        float4 o4;
        o4.x = TEMP_F * acc[r][0]; o4.y = TEMP_F * acc[r][1];
        o4.z = TEMP_F * acc[r][2]; o4.w = TEMP_F * acc[r][3];
        *(float4*)&Cb[(size_t)(i0 + r0 + r) * SEQ + j0 + c0] = o4;
    }
}

// ---------------- softmax over rows (in-place), optional mvec = aff @ label ----------------
__global__ __launch_bounds__(256) void k_softmax(float* __restrict__ Aff,
                                                 const float* __restrict__ labelp,
                                                 float* __restrict__ mvec, int b0) {
    const int bz = blockIdx.y, b = b0 + bz;
    const int q = blockIdx.x;
    float* row = Aff + ((size_t)bz * SEQ + q) * SEQ;
    const int t = threadIdx.x;
    __shared__ float red[256];
    float4 v = ((const float4*)row)[t];
    float m4 = fmaxf(fmaxf(v.x, v.y), fmaxf(v.z, v.w));
    red[t] = m4;
    __syncthreads();
#pragma unroll
    for (int o = 128; o > 0; o >>= 1) { if (t < o) red[t] = fmaxf(red[t], red[t + o]); __syncthreads(); }
    const float mx = red[0];
    __syncthreads();
    float e0 = __expf(v.x - mx), e1 = __expf(v.y - mx), e2 = __expf(v.z - mx), e3 = __expf(v.w - mx);
    red[t] = e0 + e1 + e2 + e3;
    __syncthreads();
#pragma unroll
    for (int o = 128; o > 0; o >>= 1) { if (t < o) red[t] += red[t + o]; __syncthreads(); }
    const float inv = 1.0f / red[0];
    float4 o4; o4.x = e0 * inv; o4.y = e1 * inv; o4.z = e2 * inv; o4.w = e3 * inv;
    ((float4*)row)[t] = o4;
    if (labelp) {
        __syncthreads();
        const float4 l = ((const float4*)(labelp + (size_t)b * SEQ))[t];
        red[t] = o4.x * l.x + o4.y * l.y + o4.z * l.z + o4.w * l.w;
        __syncthreads();
#pragma unroll
        for (int o = 128; o > 0; o >>= 1) { if (t < o) red[t] += red[t + o]; __syncthreads(); }
        if (t == 0) mvec[(size_t)b * SEQ + q] = red[0];
    }
}

// ---------------- PV: C[b][i][d] = sum_s Aff[bz][i][s] * V[b][s][d] (*label[b][s] optional) ----------------
__global__ __launch_bounds__(256) void k_pv(const float* __restrict__ Aff,
                                            const float* __restrict__ V,
                                            const float* __restrict__ vlabel,
                                            float* __restrict__ Cout, int b0) {
    const int bz = blockIdx.z, b = b0 + bz;
    const float* Ab = Aff + (size_t)bz * SEQ * SEQ;
    const float* Vb = V + (size_t)b * SEQ * DM;
    float* Cb = Cout + (size_t)b * SEQ * DM;
    const int i0 = blockIdx.y * 64, j0 = blockIdx.x * 64;
    __shared__ float As[64][17];
    __shared__ float Bs[16][68];
    const int tid = threadIdx.x;
    const int ai = tid >> 2, ak = (tid & 3) * 4;
    const int bk = tid >> 4, bj = (tid & 15) * 4;
    const int r0 = (tid >> 4) * 4, c0 = (tid & 15) * 4;
    float acc[4][4] = {};
    for (int k0 = 0; k0 < SEQ; k0 += 16) {
        float4 a4 = *(const float4*)&Ab[(size_t)(i0 + ai) * SEQ + k0 + ak];
        As[ai][ak] = a4.x; As[ai][ak + 1] = a4.y; As[ai][ak + 2] = a4.z; As[ai][ak + 3] = a4.w;
        float4 v4 = *(const float4*)&Vb[(size_t)(k0 + bk) * DM + j0 + bj];
        if (vlabel) {
            const float lv = vlabel[(size_t)b * SEQ + k0 + bk];
            v4.x *= lv; v4.y *= lv; v4.z *= lv; v4.w *= lv;
        }
        *(float4*)&Bs[bk][bj] = v4;
        __syncthreads();
#pragma unroll
        for (int kk = 0; kk < 16; ++kk) {
            float a[4];
#pragma unroll
            for (int r = 0; r < 4; ++r) a[r] = As[r0 + r][kk];
            float4 bv = *(const float4*)&Bs[kk][c0];
#pragma unroll
            for (int r = 0; r < 4; ++r) {
                acc[r][0] = fmaf(a[r], bv.x, acc[r][0]);
                acc[r][1] = fmaf(a[r], bv.y, acc[r][1]);
                acc[r][2] = fmaf(a[r], bv.z, acc[r][2]);
                acc[r][3] = fmaf(a[r], bv.w, acc[r][3]);
            }
        }
        __syncthreads();
    }
#pragma unroll
    for (int r = 0; r < 4; ++r) {
        float4 o4; o4.x = acc[r][0]; o4.y = acc[r][1]; o4.z = acc[r][2]; o4.w = acc[r][3];
        *(float4*)&Cb[(size_t)(i0 + r0 + r) * DM + j0 + c0] = o4;
    }
}

// ---------------- zero SS ----------------
__global__ void k_zero(float* __restrict__ SSb) {
    if (threadIdx.x < NB) SSb[threadIdx.x] = 0.0f;
}

// ---------------- elementwise combine + sum-of-squares accumulate ----------------
// mode 0: dst = A + Bt ; mode 1: dst = A * mvec[b][row]
__global__ __launch_bounds__(256) void k_elem_ss(const float* __restrict__ Aa,
                                                 const float* __restrict__ Bt,
                                                 const float* __restrict__ mv,
                                                 float* __restrict__ dst,
                                                 float* __restrict__ SSb, int mode) {
    const int b = blockIdx.y;
    const int idx = blockIdx.x * 256 + threadIdx.x;      // float4 index within batch
    const size_t i4 = (size_t)b * (SEQ * DM / 4) + idx;
    float4 a = ((const float4*)Aa)[i4];
    float4 r;
    if (mode == 0) {
        float4 bb = ((const float4*)Bt)[i4];
        r.x = a.x + bb.x; r.y = a.y + bb.y; r.z = a.z + bb.z; r.w = a.w + bb.w;
    } else {
        const int qrow = idx >> 7;  // idx / (DM/4)
        const float m = mv[(size_t)b * SEQ + qrow];
        r.x = a.x * m; r.y = a.y * m; r.z = a.z * m; r.w = a.w * m;
    }
    ((float4*)dst)[i4] = r;
    float ssq = r.x * r.x + r.y * r.y + r.z * r.z + r.w * r.w;
    __shared__ float red[256];
    red[threadIdx.x] = ssq;
    __syncthreads();
#pragma unroll
    for (int o = 128; o > 0; o >>= 1) { if (threadIdx.x < o) red[threadIdx.x] += red[threadIdx.x + o]; __syncthreads(); }
    if (threadIdx.x == 0) atomicAdd(&SSb[b], red[0]);
}

// ---------------- scale by instance-norm factor ----------------
__global__ __launch_bounds__(256) void k_scale(float* __restrict__ dst, const float* __restrict__ SSb) {
    const int b = blockIdx.y;
    const size_t i4 = (size_t)b * (SEQ * DM / 4) + blockIdx.x * 256 + threadIdx.x;
    const float ss = SSb[b];
    const float f = NORM_SCALE_F * sqrtf((float)(DM * SEQ) / (ss + 1e-5f));
    float4 v = ((float4*)dst)[i4];
    v.x *= f; v.y *= f; v.z *= f; v.w *= f;
    ((float4*)dst)[i4] = v;
}

extern "C" void kernel_launch(void* const* d_in, const int* in_sizes, int n_in,
                              void* d_out, int out_size, void* d_ws, size_t ws_size,
                              hipStream_t stream) {
    const float* train_feat = (const float*)d_in[0];
    const float* test_feat  = (const float*)d_in[1];
    const float* label      = (const float*)d_in[2];
    const float* WKs        = (const float*)d_in[3];
    const float* bKs        = (const float*)d_in[4];
    const float* WKc        = (const float*)d_in[5];
    const float* bKc        = (const float*)d_in[6];
    float* out = (float*)d_out;
    float* w = (float*)d_ws;

    const size_t SBD = (size_t)NB * SEQ * DM;   // 8,388,608
    const size_t SBK = (size_t)NB * SEQ * KD;   // 2,097,152
    float* X    = w;
    float* MEM  = w + SBD;
    float* T    = w + 2 * SBD;
    float* T2   = w + 3 * SBD;
    float* W1   = w + 4 * SBD;
    float* WKM  = W1 + SBK;
    float* MVEC = WKM + SBK;
    float* SSb  = MVEC + (size_t)NB * SEQ;
    float* AFF  = SSb + 64;

    const size_t used = (size_t)(AFF - w);
    const size_t wsf = ws_size / 4;
    int cap = 1;
    if (wsf > used) {
        size_t c = (wsf - used) / ((size_t)SEQ * SEQ);
        if (c < 1) c = 1;
        if (c > NB) c = NB;
        cap = (int)c;
    }

    const dim3 gT_in(DM / 32, SEQ / 32, NB), bT(32, 8);
    const dim3 gT_out(SEQ / 32, DM / 32, NB);
    const dim3 gEW(512, NB);

    auto inorm = [&](const float* Aa, const float* Bt, const float* mv, float* dst, int mode) {
        k_zero<<<1, 64, 0, stream>>>(SSb);
        k_elem_ss<<<gEW, 256, 0, stream>>>(Aa, Bt, mv, dst, SSb, mode);
        k_scale<<<gEW, 256, 0, stream>>>(dst, SSb);
    };

    auto self_attn_norm = [&]() {  // X = inorm(X + attn_self(X))
        k_proj<<<NB * SEQ / 8, 128, 0, stream>>>(X, WKs, bKs, W1);
        for (int b0 = 0; b0 < NB; b0 += cap) {
            int nb = (NB - b0 < cap) ? NB - b0 : cap;
            k_qk<<<dim3(16, 16, nb), 256, 0, stream>>>(W1, W1, AFF, b0);
            k_softmax<<<dim3(SEQ, nb), 256, 0, stream>>>(AFF, nullptr, nullptr, b0);
            k_pv<<<dim3(8, 16, nb), 256, 0, stream>>>(AFF, X, nullptr, T, b0);
        }
        inorm(X, T, nullptr, X, 0);
    };

    auto cross_attn = [&]() {  // T = t3 = aff@(MEM*label), MVEC = aff@label ; aff from (X, MEM)
        k_proj<<<NB * SEQ / 8, 128, 0, stream>>>(X, WKc, bKc, W1);
        for (int b0 = 0; b0 < NB; b0 += cap) {
            int nb = (NB - b0 < cap) ? NB - b0 : cap;
            k_qk<<<dim3(16, 16, nb), 256, 0, stream>>>(W1, WKM, AFF, b0);
            k_softmax<<<dim3(SEQ, nb), 256, 0, stream>>>(AFF, label, MVEC, b0);
            k_pv<<<dim3(8, 16, nb), 256, 0, stream>>>(AFF, MEM, label, T, b0);
        }
    };

    // ---------------- encoder ----------------
    k_transpose_in<<<gT_in, bT, 0, stream>>>(train_feat, X);
    self_attn_norm();
    self_attn_norm();
    hipMemcpyAsync(MEM, X, SBD * sizeof(float), hipMemcpyDeviceToDevice, stream);
    k_proj<<<NB * SEQ / 8, 128, 0, stream>>>(MEM, WKc, bKc, WKM);

    // ---------------- decoder (runs twice) ----------------
    auto decoder = [&](const float* feat, size_t off) {
        k_transpose_in<<<gT_in, bT, 0, stream>>>(feat, X);
        for (int l = 0; l < 2; ++l) {
            self_attn_norm();
            cross_attn();
            inorm(X, nullptr, MVEC, T2, 1);   // t2 = inorm(x * mask)
            inorm(X, T, nullptr, T, 0);       // t4 = inorm(x + t3)  (in T)
            inorm(T2, T, nullptr, X, 0);      // x  = inorm(t2 + t4)
        }
        k_transpose_out<<<gT_out, bT, 0, stream>>>(X, out + off);
    };
    decoder(train_feat, 0);
    decoder(test_feat, SBD);
}

// Round 2
// 4225.626 us; speedup vs baseline: 1.5594x; 1.5594x over previous
//
#include <hip/hip_runtime.h>
#include <math.h>

#define NB 16
#define SEQ 1024
#define DM 512
#define KD 128
#define TEMP_F 30.0f
#define NS_F 0.011048543456039805f   // sqrt(1/8192)
#define DS_F 524288.0f               // D*H*W = 512*1024

typedef short bf16x8 __attribute__((ext_vector_type(8)));
typedef float f32x4 __attribute__((ext_vector_type(4)));
typedef unsigned short us4 __attribute__((ext_vector_type(4)));
typedef unsigned short us8 __attribute__((ext_vector_type(8)));

__device__ __forceinline__ unsigned short f2bf(float x) {
    union { float f; unsigned u; } v; v.f = x;
    unsigned r = v.u + 0x7fffu + ((v.u >> 16) & 1u);
    return (unsigned short)(r >> 16);
}
__device__ __forceinline__ float bf2f(unsigned short h) {
    union { unsigned u; float f; } v; v.u = ((unsigned)h) << 16;
    return v.f;
}

// global -> LDS async 16B/lane. lds dst must be wave-uniform base (+lane*16 implicit).
#define GLL16(gp, lp) __builtin_amdgcn_global_load_lds( \
    (__attribute__((address_space(1))) void*)(unsigned long long)(gp), \
    (__attribute__((address_space(3))) void*)(unsigned)(unsigned long long)(lp), 16, 0, 0)

// ---------------- transpose in: src [B][D][S] -> dst [B][S][D] f32 ----------------
__global__ __launch_bounds__(256) void k_transpose_in(const float* __restrict__ src,
                                                      float* __restrict__ dst) {
    __shared__ float tile[32][33];
    const int b = blockIdx.z;
    const int d0 = blockIdx.x * 32;
    const int s0 = blockIdx.y * 32;
    const int tx = threadIdx.x, ty = threadIdx.y;  // 32x8
    const float* p = src + (size_t)b * DM * SEQ;
    float* q = dst + (size_t)b * SEQ * DM;
#pragma unroll
    for (int j = 0; j < 32; j += 8)
        tile[ty + j][tx] = p[(size_t)(d0 + ty + j) * SEQ + s0 + tx];
    __syncthreads();
#pragma unroll
    for (int j = 0; j < 32; j += 8)
        q[(size_t)(s0 + ty + j) * DM + d0 + tx] = tile[tx][ty + j];
}

// ---------------- cast f32 [B][D][S] -> bf16 same layout ----------------
__global__ __launch_bounds__(256) void k_cast(const float* __restrict__ src,
                                              unsigned short* __restrict__ dst) {
    const size_t i = ((size_t)blockIdx.x * 256 + threadIdx.x) * 8;
    float4 a = *(const float4*)(src + i);
    float4 b = *(const float4*)(src + i + 4);
    us8 o;
    o[0] = f2bf(a.x); o[1] = f2bf(a.y); o[2] = f2bf(a.z); o[3] = f2bf(a.w);
    o[4] = f2bf(b.x); o[5] = f2bf(b.y); o[6] = f2bf(b.z); o[7] = f2bf(b.w);
    *(us8*)(dst + i) = o;
}

// ---------------- MEMLT[b][d][s] = MEMT[b][d][s] * label[b][s] ----------------
__global__ __launch_bounds__(256) void k_mklabel(const unsigned short* __restrict__ MT,
                                                 const float* __restrict__ label,
                                                 unsigned short* __restrict__ ML) {
    const int b = blockIdx.y;
    const size_t off = ((size_t)blockIdx.x * 256 + threadIdx.x) * 8;
    const int s = (int)(off & (SEQ - 1));
    const size_t o = (size_t)b * DM * SEQ + off;
    us8 v = *(const us8*)(MT + o);
    const float4 l0 = *(const float4*)(label + (size_t)b * SEQ + s);
    const float4 l1 = *(const float4*)(label + (size_t)b * SEQ + s + 4);
    us8 r;
    r[0] = f2bf(bf2f(v[0]) * l0.x); r[1] = f2bf(bf2f(v[1]) * l0.y);
    r[2] = f2bf(bf2f(v[2]) * l0.z); r[3] = f2bf(bf2f(v[3]) * l0.w);
    r[4] = f2bf(bf2f(v[4]) * l1.x); r[5] = f2bf(bf2f(v[5]) * l1.y);
    r[6] = f2bf(bf2f(v[6]) * l1.z); r[7] = f2bf(bf2f(v[7]) * l1.w);
    *(us8*)(ML + o) = r;
}

// ---------------- projection + l2norm -> bf16 hi/lo ----------------
__global__ __launch_bounds__(128) void k_proj(const float* __restrict__ Xp,
                                              const float* __restrict__ WK,
                                              const float* __restrict__ bK,
                                              unsigned short* __restrict__ Wh,
                                              unsigned short* __restrict__ Wl) {
    const int row0 = blockIdx.x * 8;
    const int k = threadIdx.x;
    __shared__ float xr[8][DM];
#pragma unroll
    for (int r = 0; r < 8; ++r)
        ((float4*)xr[r])[k] = ((const float4*)(Xp + (size_t)(row0 + r) * DM))[k];
    __syncthreads();
    float acc[8];
    const float bv = bK[k];
#pragma unroll
    for (int r = 0; r < 8; ++r) acc[r] = bv;
    for (int d = 0; d < DM; d += 4) {
        const float w0 = WK[(d + 0) * KD + k];
        const float w1 = WK[(d + 1) * KD + k];
        const float w2 = WK[(d + 2) * KD + k];
        const float w3 = WK[(d + 3) * KD + k];
#pragma unroll
        for (int r = 0; r < 8; ++r) {
            float4 xv = *(const float4*)&xr[r][d];
            acc[r] = fmaf(xv.x, w0, acc[r]);
            acc[r] = fmaf(xv.y, w1, acc[r]);
            acc[r] = fmaf(xv.z, w2, acc[r]);
            acc[r] = fmaf(xv.w, w3, acc[r]);
        }
    }
    __shared__ float part[2][8];
    const int lane = k & 63, wv = k >> 6;
#pragma unroll
    for (int r = 0; r < 8; ++r) {
        float v = acc[r] * acc[r];
#pragma unroll
        for (int o = 32; o > 0; o >>= 1) v += __shfl_xor(v, o, 64);
        if (lane == 0) part[wv][r] = v;
    }
    __syncthreads();
#pragma unroll
    for (int r = 0; r < 8; ++r) {
        float n = fmaxf(sqrtf(part[0][r] + part[1][r]), 1e-12f);
        const float wvv = acc[r] / n;
        const unsigned short h = f2bf(wvv);
        Wh[(size_t)(row0 + r) * KD + k] = h;
        Wl[(size_t)(row0 + r) * KD + k] = f2bf(wvv - bf2f(h));
    }
}

// ---------------- QK^T MFMA (bf16 hi/lo x3): Aff = TEMP * Wq . Wk^T ----------------
__global__ __launch_bounds__(256) void k_qk(const unsigned short* __restrict__ Qh,
                                            const unsigned short* __restrict__ Ql,
                                            const unsigned short* __restrict__ Kh,
                                            const unsigned short* __restrict__ Kl,
                                            float* __restrict__ Aff, int b0) {
    const int bz = blockIdx.z, b = b0 + bz;
    const int i0 = blockIdx.y * 128, j0 = blockIdx.x * 128;
    const size_t ob = (size_t)b * SEQ * KD;
    const unsigned short* Ah_g = Qh + ob;
    const unsigned short* Al_g = Ql + ob;
    const unsigned short* Bh_g = Kh + ob;
    const unsigned short* Bl_g = Kl + ob;
    __shared__ short Ah[128 * 32], Al[128 * 32], Bh[128 * 32], Bl[128 * 32];
    const int tid = threadIdx.x, w = tid >> 6, l = tid & 63;
    const int wm = (w >> 1) * 64, wn = (w & 1) * 64;
    const int srow = l >> 2, scol = (l & 3) * 8;
    f32x4 acc[4][4] = {};
    for (int k0 = 0; k0 < KD; k0 += 32) {
#pragma unroll
        for (int cc = 0; cc < 2; ++cc) {
            const int c = 2 * w + cc;
            const size_t ra = (size_t)(i0 + c * 16 + srow) * KD + k0 + scol;
            const size_t rb = (size_t)(j0 + c * 16 + srow) * KD + k0 + scol;
            GLL16(Ah_g + ra, &Ah[c * 512]);
            GLL16(Al_g + ra, &Al[c * 512]);
            GLL16(Bh_g + rb, &Bh[c * 512]);
            GLL16(Bl_g + rb, &Bl[c * 512]);
        }
        __syncthreads();
        const int lr = l & 15, lk = (l >> 4) * 8;
        bf16x8 ah[4], al[4], bh[4], bl[4];
#pragma unroll
        for (int f = 0; f < 4; ++f) {
            ah[f] = *(const bf16x8*)&Ah[(wm + f * 16 + lr) * 32 + lk];
            al[f] = *(const bf16x8*)&Al[(wm + f * 16 + lr) * 32 + lk];
            bh[f] = *(const bf16x8*)&Bh[(wn + f * 16 + lr) * 32 + lk];
            bl[f] = *(const bf16x8*)&Bl[(wn + f * 16 + lr) * 32 + lk];
        }
#pragma unroll
        for (int fm = 0; fm < 4; ++fm)
#pragma unroll
            for (int fn = 0; fn < 4; ++fn) {
                acc[fm][fn] = __builtin_amdgcn_mfma_f32_16x16x32_bf16(ah[fm], bh[fn], acc[fm][fn], 0, 0, 0);
                acc[fm][fn] = __builtin_amdgcn_mfma_f32_16x16x32_bf16(ah[fm], bl[fn], acc[fm][fn], 0, 0, 0);
                acc[fm][fn] = __builtin_amdgcn_mfma_f32_16x16x32_bf16(al[fm], bh[fn], acc[fm][fn], 0, 0, 0);
            }
        __syncthreads();
    }
    float* Cb = Aff + (size_t)bz * SEQ * SEQ;
    const int er = l & 15, eq = (l >> 4) * 4;
#pragma unroll
    for (int fm = 0; fm < 4; ++fm)
#pragma unroll
        for (int fn = 0; fn < 4; ++fn)
#pragma unroll
            for (int r = 0; r < 4; ++r)
                Cb[(size_t)(i0 + wm + fm * 16 + eq + r) * SEQ + j0 + wn + fn * 16 + er] =
                    TEMP_F * acc[fm][fn][r];
}

// ---------------- softmax rows -> P bf16 (normalized), optional mvec ----------------
__global__ __launch_bounds__(256) void k_softmax(const float* __restrict__ Aff,
                                                 unsigned short* __restrict__ P,
                                                 const float* __restrict__ labelp,
                                                 float* __restrict__ mvec, int b0) {
    const int bz = blockIdx.y, b = b0 + bz;
    const int q = blockIdx.x;
    const float* row = Aff + ((size_t)bz * SEQ + q) * SEQ;
    unsigned short* prow = P + ((size_t)bz * SEQ + q) * SEQ;
    const int t = threadIdx.x;
    __shared__ float red[256];
    float4 v = ((const float4*)row)[t];
    red[t] = fmaxf(fmaxf(v.x, v.y), fmaxf(v.z, v.w));
    __syncthreads();
#pragma unroll
    for (int o = 128; o > 0; o >>= 1) { if (t < o) red[t] = fmaxf(red[t], red[t + o]); __syncthreads(); }
    const float mx = red[0];
    __syncthreads();
    float e0 = __expf(v.x - mx), e1 = __expf(v.y - mx), e2 = __expf(v.z - mx), e3 = __expf(v.w - mx);
    red[t] = e0 + e1 + e2 + e3;
    __syncthreads();
#pragma unroll
    for (int o = 128; o > 0; o >>= 1) { if (t < o) red[t] += red[t + o]; __syncthreads(); }
    const float inv = 1.0f / red[0];
    e0 *= inv; e1 *= inv; e2 *= inv; e3 *= inv;
    us4 pw; pw.x = f2bf(e0); pw.y = f2bf(e1); pw.z = f2bf(e2); pw.w = f2bf(e3);
    ((us4*)prow)[t] = pw;
    if (labelp) {
        __syncthreads();
        const float4 lb = ((const float4*)(labelp + (size_t)b * SEQ))[t];
        red[t] = e0 * lb.x + e1 * lb.y + e2 * lb.z + e3 * lb.w;
        __syncthreads();
#pragma unroll
        for (int o = 128; o > 0; o >>= 1) { if (t < o) red[t] += red[t + o]; __syncthreads(); }
        if (t == 0) mvec[(size_t)b * SEQ + q] = red[0];
    }
}

// ---------------- PV MFMA: C[q][d] = P[q][s] x VT[d][s]; mode 1: +=X, ssq->SS ----------------
__global__ __launch_bounds__(256) void k_pv(const unsigned short* __restrict__ P,
                                            const unsigned short* __restrict__ VT,
                                            const float* __restrict__ Xres,
                                            float* __restrict__ Cout,
                                            float* __restrict__ SS, int b0, int mode) {
    const int bz = blockIdx.z, b = b0 + bz;
    const int i0 = blockIdx.y * 128, j0 = blockIdx.x * 128;
    const unsigned short* Pb = P + (size_t)bz * SEQ * SEQ;
    const unsigned short* Vb = VT + (size_t)b * DM * SEQ;
    __shared__ short Pa[128 * 64], Vv[128 * 64];
    const int tid = threadIdx.x, w = tid >> 6, l = tid & 63;
    const int wm = (w >> 1) * 64, wn = (w & 1) * 64;
    const int srow = l >> 3, scol = (l & 7) * 8;
    f32x4 acc[4][4] = {};
    for (int k0 = 0; k0 < SEQ; k0 += 64) {
#pragma unroll
        for (int cc = 0; cc < 4; ++cc) {
            const int c = 4 * w + cc;
            GLL16(Pb + (size_t)(i0 + c * 8 + srow) * SEQ + k0 + scol, &Pa[c * 512]);
            GLL16(Vb + (size_t)(j0 + c * 8 + srow) * SEQ + k0 + scol, &Vv[c * 512]);
        }
        __syncthreads();
        const int lr = l & 15, lk = (l >> 4) * 8;
#pragma unroll
        for (int kc = 0; kc < 2; ++kc) {
            bf16x8 a[4], bb[4];
#pragma unroll
            for (int f = 0; f < 4; ++f) {
                a[f] = *(const bf16x8*)&Pa[(wm + f * 16 + lr) * 64 + kc * 32 + lk];
                bb[f] = *(const bf16x8*)&Vv[(wn + f * 16 + lr) * 64 + kc * 32 + lk];
            }
#pragma unroll
            for (int fm = 0; fm < 4; ++fm)
#pragma unroll
                for (int fn = 0; fn < 4; ++fn)
                    acc[fm][fn] = __builtin_amdgcn_mfma_f32_16x16x32_bf16(a[fm], bb[fn], acc[fm][fn], 0, 0, 0);
        }
        __syncthreads();
    }
    float ssq = 0.0f;
    const int er = l & 15, eq = (l >> 4) * 4;
#pragma unroll
    for (int fm = 0; fm < 4; ++fm)
#pragma unroll
        for (int fn = 0; fn < 4; ++fn)
#pragma unroll
            for (int r = 0; r < 4; ++r) {
                const int row = i0 + wm + fm * 16 + eq + r;
                const int col = j0 + wn + fn * 16 + er;
                float v = acc[fm][fn][r];
                const size_t o = ((size_t)b * SEQ + row) * DM + col;
                if (mode == 1) { v += Xres[o]; ssq += v * v; }
                Cout[o] = v;
            }
    if (mode == 1) {
#pragma unroll
        for (int off = 32; off > 0; off >>= 1) ssq += __shfl_xor(ssq, off, 64);
        __shared__ float ps[4];
        if (l == 0) ps[w] = ssq;
        __syncthreads();
        if (tid == 0) atomicAdd(&SS[b], ps[0] + ps[1] + ps[2] + ps[3]);
    }
}

// ---------------- zero SS (64 floats) ----------------
__global__ void k_zero(float* __restrict__ SSb) {
    if (threadIdx.x < 64) SSb[threadIdx.x] = 0.0f;
}

// ---------------- reduce3: ssa=sum(x*m)^2, ssb=sum(x+t)^2, ssab=sum((x*m)(x+t)) ----------------
__global__ __launch_bounds__(256) void k_reduce3(const float* __restrict__ X,
                                                 const float* __restrict__ T,
                                                 const float* __restrict__ mv,
                                                 float* __restrict__ SS) {
    const int b = blockIdx.y;
    const int idx = blockIdx.x * 256 + threadIdx.x;
    const size_t i4 = (size_t)b * (SEQ * DM / 4) + idx;
    const float4 x = ((const float4*)X)[i4];
    const float4 t = ((const float4*)T)[i4];
    const float m = mv[(size_t)b * SEQ + (idx >> 7)];
    const float ax = x.x * m, ay = x.y * m, az = x.z * m, aw = x.w * m;
    const float bx = x.x + t.x, by = x.y + t.y, bz2 = x.z + t.z, bw = x.w + t.w;
    float sa = ax * ax + ay * ay + az * az + aw * aw;
    float sb = bx * bx + by * by + bz2 * bz2 + bw * bw;
    float sab = ax * bx + ay * by + az * bz2 + aw * bw;
    const int l = threadIdx.x & 63;
#pragma unroll
    for (int o = 32; o > 0; o >>= 1) {
        sa += __shfl_xor(sa, o, 64);
        sb += __shfl_xor(sb, o, 64);
        sab += __shfl_xor(sab, o, 64);
    }
    if (l == 0) {
        atomicAdd(&SS[b], sa);
        atomicAdd(&SS[NB + b], sb);
        atomicAdd(&SS[2 * NB + b], sab);
    }
}

// ---------------- finish: compute v, write X [S][D] f32 + transposed bf16/f32 ----------------
// mode 0: v = f*T ; mode 1: v = f3*(f1*x*mv + f2*(x+t))
__global__ __launch_bounds__(256) void k_finish(const float* __restrict__ Xin,
                                                const float* __restrict__ Tin,
                                                const float* __restrict__ mv,
                                                const float* __restrict__ SS,
                                                float* __restrict__ Xout,
                                                unsigned short* __restrict__ XTb,
                                                float* __restrict__ XTf,
                                                int mode, int writeX) {
    const int b = blockIdx.z;
    const int s0 = blockIdx.x * 32, d0 = blockIdx.y * 32;
    const int tx = threadIdx.x, ty = threadIdx.y;
    __shared__ float tile[32][33];
    float f1 = 0.f, f2 = 0.f, f3;
    if (mode == 0) {
        f3 = NS_F * sqrtf(DS_F / (SS[b] + 1e-5f));
    } else {
        const float ssa = SS[b], ssb = SS[NB + b], ssab = SS[2 * NB + b];
        f1 = NS_F * sqrtf(DS_F / (ssa + 1e-5f));
        f2 = NS_F * sqrtf(DS_F / (ssb + 1e-5f));
        const float ssc = f1 * f1 * ssa + 2.f * f1 * f2 * ssab + f2 * f2 * ssb;
        f3 = NS_F * sqrtf(DS_F / (ssc + 1e-5f));
    }
#pragma unroll
    for (int j = 0; j < 4; ++j) {
        const int s = s0 + ty + j * 8;
        const size_t o = ((size_t)b * SEQ + s) * DM + d0 + tx;
        float v;
        if (mode == 0) v = f3 * Tin[o];
        else {
            const float x = Xin[o];
            v = f3 * (f1 * x * mv[(size_t)b * SEQ + s] + f2 * (x + Tin[o]));
        }
        if (writeX) Xout[o] = v;
        tile[ty + j * 8][tx] = v;
    }
    __syncthreads();
#pragma unroll
    for (int j = 0; j < 4; ++j) {
        const int d = d0 + ty + j * 8;
        const int s = s0 + tx;
        const float v = tile[tx][ty + j * 8];
        const size_t o = ((size_t)b * DM + d) * SEQ + s;
        if (XTb) XTb[o] = f2bf(v);
        else XTf[o] = v;
    }
}

extern "C" void kernel_launch(void* const* d_in, const int* in_sizes, int n_in,
                              void* d_out, int out_size, void* d_ws, size_t ws_size,
                              hipStream_t stream) {
    const float* train_feat = (const float*)d_in[0];
    const float* test_feat  = (const float*)d_in[1];
    const float* label      = (const float*)d_in[2];
    const float* WKs        = (const float*)d_in[3];
    const float* bKs        = (const float*)d_in[4];
    const float* WKc        = (const float*)d_in[5];
    const float* bKc        = (const float*)d_in[6];
    float* out = (float*)d_out;
    float* w = (float*)d_ws;

    const size_t SBD = (size_t)NB * SEQ * DM;   // 8,388,608
    const size_t SBK = (size_t)NB * SEQ * KD;   // 2,097,152

    float* X = w;                                          // SBD f32
    float* T = X + SBD;                                    // SBD f32
    unsigned short* XTd   = (unsigned short*)(T + SBD);    // SBD bf16
    unsigned short* MEMT  = XTd + SBD;                     // SBD bf16
    unsigned short* MEMLT = MEMT + SBD;                    // SBD bf16
    unsigned short* W1h   = MEMLT + SBD;                   // SBK bf16
    unsigned short* W1l   = W1h + SBK;
    unsigned short* WKMh  = W1l + SBK;
    unsigned short* WKMl  = WKMh + SBK;
    float* MVEC = (float*)(WKMl + SBK);                    // NB*SEQ f32
    float* SS   = MVEC + (size_t)NB * SEQ;                 // 64 f32
    float* AFF  = SS + 64;                                 // cap*SEQ*SEQ f32

    const size_t fixed = (size_t)(AFF - w);
    const size_t per = (size_t)SEQ * SEQ + (size_t)SEQ * SEQ / 2;  // AFF f32 + P bf16
    const size_t wsf = ws_size / 4;
    int cap = 1;
    if (wsf > fixed) {
        size_t c = (wsf - fixed) / per;
        if (c < 1) c = 1;
        if (c > NB) c = NB;
        cap = (int)c;
    }
    unsigned short* Pbuf = (unsigned short*)(AFF + (size_t)cap * SEQ * SEQ);

    const dim3 gT_in(DM / 32, SEQ / 32, NB), bT(32, 8);
    const dim3 gFin(SEQ / 32, DM / 32, NB);

    auto attn = [&](const unsigned short* Qh, const unsigned short* Ql,
                    const unsigned short* Kh, const unsigned short* Kl,
                    const unsigned short* VT, const float* labelp, float* mvp,
                    const float* Xres, int pvmode) {
        for (int b0 = 0; b0 < NB; b0 += cap) {
            const int nb = (NB - b0 < cap) ? NB - b0 : cap;
            k_qk<<<dim3(8, 8, nb), 256, 0, stream>>>(Qh, Ql, Kh, Kl, AFF, b0);
            k_softmax<<<dim3(SEQ, nb), 256, 0, stream>>>(AFF, Pbuf, labelp, mvp, b0);
            k_pv<<<dim3(4, 8, nb), 256, 0, stream>>>(Pbuf, VT, Xres, T, SS, b0, pvmode);
        }
    };

    // ---------------- encoder ----------------
    k_transpose_in<<<gT_in, bT, 0, stream>>>(train_feat, X);
    k_cast<<<SBD / 8 / 256, 256, 0, stream>>>(train_feat, MEMT);
    for (int l = 0; l < 2; ++l) {
        k_proj<<<NB * SEQ / 8, 128, 0, stream>>>(X, WKs, bKs, W1h, W1l);
        k_zero<<<1, 64, 0, stream>>>(SS);
        attn(W1h, W1l, W1h, W1l, MEMT, nullptr, nullptr, X, 1);
        k_finish<<<gFin, bT, 0, stream>>>(nullptr, T, nullptr, SS, X, MEMT, nullptr, 0, 1);
    }
    k_proj<<<NB * SEQ / 8, 128, 0, stream>>>(X, WKc, bKc, WKMh, WKMl);
    k_mklabel<<<dim3(DM * SEQ / 8 / 256, NB), 256, 0, stream>>>(MEMT, label, MEMLT);

    // ---------------- decoder (x2) ----------------
    auto decoder = [&](const float* feat, float* outp) {
        k_transpose_in<<<gT_in, bT, 0, stream>>>(feat, X);
        k_cast<<<SBD / 8 / 256, 256, 0, stream>>>(feat, XTd);
        for (int l = 0; l < 2; ++l) {
            // self-attn + inorm
            k_proj<<<NB * SEQ / 8, 128, 0, stream>>>(X, WKs, bKs, W1h, W1l);
            k_zero<<<1, 64, 0, stream>>>(SS);
            attn(W1h, W1l, W1h, W1l, XTd, nullptr, nullptr, X, 1);
            k_finish<<<gFin, bT, 0, stream>>>(nullptr, T, nullptr, SS, X, XTd, nullptr, 0, 1);
            // cross-attn: T = t3, MVEC = mask row-scalars
            k_proj<<<NB * SEQ / 8, 128, 0, stream>>>(X, WKc, bKc, W1h, W1l);
            attn(W1h, W1l, WKMh, WKMl, MEMLT, label, MVEC, nullptr, 0);
            // fused triple instance-norm
            k_zero<<<1, 64, 0, stream>>>(SS);
            k_reduce3<<<dim3(SEQ * DM / 4 / 256, NB), 256, 0, stream>>>(X, T, MVEC, SS);
            if (l == 0)
                k_finish<<<gFin, bT, 0, stream>>>(X, T, MVEC, SS, X, XTd, nullptr, 1, 1);
            else
                k_finish<<<gFin, bT, 0, stream>>>(X, T, MVEC, SS, X, nullptr, outp, 1, 0);
        }
    };
    decoder(train_feat, out);
    decoder(test_feat, out + SBD);
}

// Round 3
// 1879.481 us; speedup vs baseline: 3.5059x; 2.2483x over previous
//
#include <hip/hip_runtime.h>
#include <math.h>

#define NB 16
#define SEQ 1024
#define DM 512
#define KD 128
#define TEMP_F 30.0f
#define NS_F 0.011048543456039805f   // sqrt(1/8192)
#define DS_F 524288.0f               // D*H*W = 512*1024

// SS layout: padded one cache line per counter: SS[(grp*NB + b) * 16]
#define SS_IDX(grp, b) (((grp) * NB + (b)) * 16)
#define SS_FLOATS 768

typedef short bf16x8 __attribute__((ext_vector_type(8)));
typedef float f32x4 __attribute__((ext_vector_type(4)));
typedef unsigned short us4 __attribute__((ext_vector_type(4)));
typedef unsigned short us8 __attribute__((ext_vector_type(8)));

__device__ __forceinline__ unsigned short f2bf(float x) {
    union { float f; unsigned u; } v; v.f = x;
    unsigned r = v.u + 0x7fffu + ((v.u >> 16) & 1u);
    return (unsigned short)(r >> 16);
}
__device__ __forceinline__ float bf2f(unsigned short h) {
    union { unsigned u; float f; } v; v.u = ((unsigned)h) << 16;
    return v.f;
}

// global -> LDS async 16B/lane. lds dst must be wave-uniform base (+lane*16 implicit).
#define GLL16(gp, lp) __builtin_amdgcn_global_load_lds( \
    (__attribute__((address_space(1))) void*)(unsigned long long)(gp), \
    (__attribute__((address_space(3))) void*)(unsigned)(unsigned long long)(lp), 16, 0, 0)

// ---------------- transpose in: src [B][D][S] -> dst [B][S][D] f32 ----------------
__global__ __launch_bounds__(256) void k_transpose_in(const float* __restrict__ src,
                                                      float* __restrict__ dst) {
    __shared__ float tile[32][33];
    const int b = blockIdx.z;
    const int d0 = blockIdx.x * 32;
    const int s0 = blockIdx.y * 32;
    const int tx = threadIdx.x, ty = threadIdx.y;  // 32x8
    const float* p = src + (size_t)b * DM * SEQ;
    float* q = dst + (size_t)b * SEQ * DM;
#pragma unroll
    for (int j = 0; j < 32; j += 8)
        tile[ty + j][tx] = p[(size_t)(d0 + ty + j) * SEQ + s0 + tx];
    __syncthreads();
#pragma unroll
    for (int j = 0; j < 32; j += 8)
        q[(size_t)(s0 + ty + j) * DM + d0 + tx] = tile[tx][ty + j];
}

// ---------------- cast f32 [B][D][S] -> bf16 same layout ----------------
__global__ __launch_bounds__(256) void k_cast(const float* __restrict__ src,
                                              unsigned short* __restrict__ dst) {
    const size_t i = ((size_t)blockIdx.x * 256 + threadIdx.x) * 8;
    float4 a = *(const float4*)(src + i);
    float4 b = *(const float4*)(src + i + 4);
    us8 o;
    o[0] = f2bf(a.x); o[1] = f2bf(a.y); o[2] = f2bf(a.z); o[3] = f2bf(a.w);
    o[4] = f2bf(b.x); o[5] = f2bf(b.y); o[6] = f2bf(b.z); o[7] = f2bf(b.w);
    *(us8*)(dst + i) = o;
}

// ---------------- MEMLT[b][d][s] = MEMT[b][d][s] * label[b][s] ----------------
__global__ __launch_bounds__(256) void k_mklabel(const unsigned short* __restrict__ MT,
                                                 const float* __restrict__ label,
                                                 unsigned short* __restrict__ ML) {
    const int b = blockIdx.y;
    const size_t off = ((size_t)blockIdx.x * 256 + threadIdx.x) * 8;
    const int s = (int)(off & (SEQ - 1));
    const size_t o = (size_t)b * DM * SEQ + off;
    us8 v = *(const us8*)(MT + o);
    const float4 l0 = *(const float4*)(label + (size_t)b * SEQ + s);
    const float4 l1 = *(const float4*)(label + (size_t)b * SEQ + s + 4);
    us8 r;
    r[0] = f2bf(bf2f(v[0]) * l0.x); r[1] = f2bf(bf2f(v[1]) * l0.y);
    r[2] = f2bf(bf2f(v[2]) * l0.z); r[3] = f2bf(bf2f(v[3]) * l0.w);
    r[4] = f2bf(bf2f(v[4]) * l1.x); r[5] = f2bf(bf2f(v[5]) * l1.y);
    r[6] = f2bf(bf2f(v[6]) * l1.z); r[7] = f2bf(bf2f(v[7]) * l1.w);
    *(us8*)(ML + o) = r;
}

// ---------------- projection + l2norm -> bf16 hi/lo ----------------
__global__ __launch_bounds__(128) void k_proj(const float* __restrict__ Xp,
                                              const float* __restrict__ WK,
                                              const float* __restrict__ bK,
                                              unsigned short* __restrict__ Wh,
                                              unsigned short* __restrict__ Wl) {
    const int row0 = blockIdx.x * 8;
    const int k = threadIdx.x;
    __shared__ float xr[8][DM];
#pragma unroll
    for (int r = 0; r < 8; ++r)
        ((float4*)xr[r])[k] = ((const float4*)(Xp + (size_t)(row0 + r) * DM))[k];
    __syncthreads();
    float acc[8];
    const float bv = bK[k];
#pragma unroll
    for (int r = 0; r < 8; ++r) acc[r] = bv;
    for (int d = 0; d < DM; d += 4) {
        const float w0 = WK[(d + 0) * KD + k];
        const float w1 = WK[(d + 1) * KD + k];
        const float w2 = WK[(d + 2) * KD + k];
        const float w3 = WK[(d + 3) * KD + k];
#pragma unroll
        for (int r = 0; r < 8; ++r) {
            float4 xv = *(const float4*)&xr[r][d];
            acc[r] = fmaf(xv.x, w0, acc[r]);
            acc[r] = fmaf(xv.y, w1, acc[r]);
            acc[r] = fmaf(xv.z, w2, acc[r]);
            acc[r] = fmaf(xv.w, w3, acc[r]);
        }
    }
    __shared__ float part[2][8];
    const int lane = k & 63, wv = k >> 6;
#pragma unroll
    for (int r = 0; r < 8; ++r) {
        float v = acc[r] * acc[r];
#pragma unroll
        for (int o = 32; o > 0; o >>= 1) v += __shfl_xor(v, o, 64);
        if (lane == 0) part[wv][r] = v;
    }
    __syncthreads();
#pragma unroll
    for (int r = 0; r < 8; ++r) {
        float n = fmaxf(sqrtf(part[0][r] + part[1][r]), 1e-12f);
        const float wvv = acc[r] / n;
        const unsigned short h = f2bf(wvv);
        Wh[(size_t)(row0 + r) * KD + k] = h;
        Wl[(size_t)(row0 + r) * KD + k] = f2bf(wvv - bf2f(h));
    }
}

// ---------------- QK^T MFMA (bf16 hi/lo x3): Aff = TEMP * Wq . Wk^T ----------------
__global__ __launch_bounds__(256) void k_qk(const unsigned short* __restrict__ Qh,
                                            const unsigned short* __restrict__ Ql,
                                            const unsigned short* __restrict__ Kh,
                                            const unsigned short* __restrict__ Kl,
                                            float* __restrict__ Aff, int b0) {
    const int bz = blockIdx.z, b = b0 + bz;
    const int i0 = blockIdx.y * 128, j0 = blockIdx.x * 128;
    const size_t ob = (size_t)b * SEQ * KD;
    const unsigned short* Ah_g = Qh + ob;
    const unsigned short* Al_g = Ql + ob;
    const unsigned short* Bh_g = Kh + ob;
    const unsigned short* Bl_g = Kl + ob;
    __shared__ short Ah[128 * 32], Al[128 * 32], Bh[128 * 32], Bl[128 * 32];
    const int tid = threadIdx.x, w = tid >> 6, l = tid & 63;
    const int wm = (w >> 1) * 64, wn = (w & 1) * 64;
    const int srow = l >> 2, scol = (l & 3) * 8;
    f32x4 acc[4][4] = {};
    for (int k0 = 0; k0 < KD; k0 += 32) {
#pragma unroll
        for (int cc = 0; cc < 2; ++cc) {
            const int c = 2 * w + cc;
            const size_t ra = (size_t)(i0 + c * 16 + srow) * KD + k0 + scol;
            const size_t rb = (size_t)(j0 + c * 16 + srow) * KD + k0 + scol;
            GLL16(Ah_g + ra, &Ah[c * 512]);
            GLL16(Al_g + ra, &Al[c * 512]);
            GLL16(Bh_g + rb, &Bh[c * 512]);
            GLL16(Bl_g + rb, &Bl[c * 512]);
        }
        __syncthreads();
        const int lr = l & 15, lk = (l >> 4) * 8;
        bf16x8 ah[4], al[4], bh[4], bl[4];
#pragma unroll
        for (int f = 0; f < 4; ++f) {
            ah[f] = *(const bf16x8*)&Ah[(wm + f * 16 + lr) * 32 + lk];
            al[f] = *(const bf16x8*)&Al[(wm + f * 16 + lr) * 32 + lk];
            bh[f] = *(const bf16x8*)&Bh[(wn + f * 16 + lr) * 32 + lk];
            bl[f] = *(const bf16x8*)&Bl[(wn + f * 16 + lr) * 32 + lk];
        }
#pragma unroll
        for (int fm = 0; fm < 4; ++fm)
#pragma unroll
            for (int fn = 0; fn < 4; ++fn) {
                acc[fm][fn] = __builtin_amdgcn_mfma_f32_16x16x32_bf16(ah[fm], bh[fn], acc[fm][fn], 0, 0, 0);
                acc[fm][fn] = __builtin_amdgcn_mfma_f32_16x16x32_bf16(ah[fm], bl[fn], acc[fm][fn], 0, 0, 0);
                acc[fm][fn] = __builtin_amdgcn_mfma_f32_16x16x32_bf16(al[fm], bh[fn], acc[fm][fn], 0, 0, 0);
            }
        __syncthreads();
    }
    float* Cb = Aff + (size_t)bz * SEQ * SEQ;
    const int er = l & 15, eq = (l >> 4) * 4;
#pragma unroll
    for (int fm = 0; fm < 4; ++fm)
#pragma unroll
        for (int fn = 0; fn < 4; ++fn)
#pragma unroll
            for (int r = 0; r < 4; ++r)
                Cb[(size_t)(i0 + wm + fm * 16 + eq + r) * SEQ + j0 + wn + fn * 16 + er] =
                    TEMP_F * acc[fm][fn][r];
}

// ---------------- softmax rows -> P bf16 (normalized), optional mvec ----------------
__global__ __launch_bounds__(256) void k_softmax(const float* __restrict__ Aff,
                                                 unsigned short* __restrict__ P,
                                                 const float* __restrict__ labelp,
                                                 float* __restrict__ mvec, int b0) {
    const int bz = blockIdx.y, b = b0 + bz;
    const int q = blockIdx.x;
    const float* row = Aff + ((size_t)bz * SEQ + q) * SEQ;
    unsigned short* prow = P + ((size_t)bz * SEQ + q) * SEQ;
    const int t = threadIdx.x;
    __shared__ float red[256];
    float4 v = ((const float4*)row)[t];
    red[t] = fmaxf(fmaxf(v.x, v.y), fmaxf(v.z, v.w));
    __syncthreads();
#pragma unroll
    for (int o = 128; o > 0; o >>= 1) { if (t < o) red[t] = fmaxf(red[t], red[t + o]); __syncthreads(); }
    const float mx = red[0];
    __syncthreads();
    float e0 = __expf(v.x - mx), e1 = __expf(v.y - mx), e2 = __expf(v.z - mx), e3 = __expf(v.w - mx);
    red[t] = e0 + e1 + e2 + e3;
    __syncthreads();
#pragma unroll
    for (int o = 128; o > 0; o >>= 1) { if (t < o) red[t] += red[t + o]; __syncthreads(); }
    const float inv = 1.0f / red[0];
    e0 *= inv; e1 *= inv; e2 *= inv; e3 *= inv;
    us4 pw; pw.x = f2bf(e0); pw.y = f2bf(e1); pw.z = f2bf(e2); pw.w = f2bf(e3);
    ((us4*)prow)[t] = pw;
    if (labelp) {
        __syncthreads();
        const float4 lb = ((const float4*)(labelp + (size_t)b * SEQ))[t];
        red[t] = e0 * lb.x + e1 * lb.y + e2 * lb.z + e3 * lb.w;
        __syncthreads();
#pragma unroll
        for (int o = 128; o > 0; o >>= 1) { if (t < o) red[t] += red[t + o]; __syncthreads(); }
        if (t == 0) mvec[(size_t)b * SEQ + q] = red[0];
    }
}

// ---------------- PV MFMA: acc = P x VT^T ----------------
// mode 1: Cout = acc + X, ssq -> SS[0][b]                       (self-attn)
// mode 2: Cout = acc + X (=x+t3); sa=(x*m)^2, sb=(x+t3)^2, sab -> SS[0..2][b]  (cross)
__global__ __launch_bounds__(256) void k_pv(const unsigned short* __restrict__ P,
                                            const unsigned short* __restrict__ VT,
                                            const float* __restrict__ Xres,
                                            const float* __restrict__ mvp,
                                            float* __restrict__ Cout,
                                            float* __restrict__ SS, int b0, int mode) {
    const int bz = blockIdx.z, b = b0 + bz;
    const int i0 = blockIdx.y * 128, j0 = blockIdx.x * 128;
    const unsigned short* Pb = P + (size_t)bz * SEQ * SEQ;
    const unsigned short* Vb = VT + (size_t)b * DM * SEQ;
    __shared__ short Pa[128 * 64], Vv[128 * 64];
    __shared__ float sh_mv[128];
    const int tid = threadIdx.x, w = tid >> 6, l = tid & 63;
    const int wm = (w >> 1) * 64, wn = (w & 1) * 64;
    const int srow = l >> 3, scol = (l & 7) * 8;
    f32x4 acc[4][4] = {};
    for (int k0 = 0; k0 < SEQ; k0 += 64) {
#pragma unroll
        for (int cc = 0; cc < 4; ++cc) {
            const int c = 4 * w + cc;
            GLL16(Pb + (size_t)(i0 + c * 8 + srow) * SEQ + k0 + scol, &Pa[c * 512]);
            GLL16(Vb + (size_t)(j0 + c * 8 + srow) * SEQ + k0 + scol, &Vv[c * 512]);
        }
        __syncthreads();
        const int lr = l & 15, lk = (l >> 4) * 8;
#pragma unroll
        for (int kc = 0; kc < 2; ++kc) {
            bf16x8 a[4], bb[4];
#pragma unroll
            for (int f = 0; f < 4; ++f) {
                a[f] = *(const bf16x8*)&Pa[(wm + f * 16 + lr) * 64 + kc * 32 + lk];
                bb[f] = *(const bf16x8*)&Vv[(wn + f * 16 + lr) * 64 + kc * 32 + lk];
            }
#pragma unroll
            for (int fm = 0; fm < 4; ++fm)
#pragma unroll
                for (int fn = 0; fn < 4; ++fn)
                    acc[fm][fn] = __builtin_amdgcn_mfma_f32_16x16x32_bf16(a[fm], bb[fn], acc[fm][fn], 0, 0, 0);
        }
        __syncthreads();
    }
    if (mode == 2) {
        if (tid < 128) sh_mv[tid] = mvp[(size_t)b * SEQ + i0 + tid];
        __syncthreads();
    }
    float sa = 0.f, sb = 0.f, sab = 0.f;
    const int er = l & 15, eq = (l >> 4) * 4;
#pragma unroll
    for (int fm = 0; fm < 4; ++fm)
#pragma unroll
        for (int fn = 0; fn < 4; ++fn)
#pragma unroll
            for (int r = 0; r < 4; ++r) {
                const int lrow = wm + fm * 16 + eq + r;
                const int col = j0 + wn + fn * 16 + er;
                float v = acc[fm][fn][r];
                const size_t o = ((size_t)b * SEQ + i0 + lrow) * DM + col;
                if (mode >= 1) {
                    const float x = Xres[o];
                    v += x;
                    sb += v * v;
                    if (mode == 2) {
                        const float a = x * sh_mv[lrow];
                        sa += a * a;
                        sab += a * v;
                    }
                }
                Cout[o] = v;
            }
    if (mode >= 1) {
#pragma unroll
        for (int off = 32; off > 0; off >>= 1) {
            sb += __shfl_xor(sb, off, 64);
            if (mode == 2) { sa += __shfl_xor(sa, off, 64); sab += __shfl_xor(sab, off, 64); }
        }
        __shared__ float ps[3][4];
        if (l == 0) { ps[0][w] = sb; ps[1][w] = sa; ps[2][w] = sab; }
        __syncthreads();
        if (tid == 0) {
            if (mode == 1) {
                atomicAdd(&SS[SS_IDX(0, b)], ps[0][0] + ps[0][1] + ps[0][2] + ps[0][3]);
            } else {
                atomicAdd(&SS[SS_IDX(0, b)], ps[1][0] + ps[1][1] + ps[1][2] + ps[1][3]);
                atomicAdd(&SS[SS_IDX(1, b)], ps[0][0] + ps[0][1] + ps[0][2] + ps[0][3]);
                atomicAdd(&SS[SS_IDX(2, b)], ps[2][0] + ps[2][1] + ps[2][2] + ps[2][3]);
            }
        }
    }
}

// ---------------- zero SS ----------------
__global__ void k_zero(float* __restrict__ SSb) {
    for (int i = threadIdx.x; i < SS_FLOATS; i += 256) SSb[i] = 0.0f;
}

// ---------------- finish: compute v, write X [S][D] f32 + transposed bf16/f32 ----------------
// mode 0: v = f*T ; mode 1: v = f3*(f1*x*mv + f2*T)  (T already holds x+t3)
__global__ __launch_bounds__(256) void k_finish(const float* __restrict__ Xin,
                                                const float* __restrict__ Tin,
                                                const float* __restrict__ mv,
                                                const float* __restrict__ SS,
                                                float* __restrict__ Xout,
                                                unsigned short* __restrict__ XTb,
                                                float* __restrict__ XTf,
                                                int mode, int writeX) {
    const int b = blockIdx.z;
    const int s0 = blockIdx.x * 32, d0 = blockIdx.y * 32;
    const int tx = threadIdx.x, ty = threadIdx.y;
    __shared__ float tile[32][33];
    float f1 = 0.f, f2 = 0.f, f3;
    if (mode == 0) {
        f3 = NS_F * sqrtf(DS_F / (SS[SS_IDX(0, b)] + 1e-5f));
    } else {
        const float ssa = SS[SS_IDX(0, b)], ssb = SS[SS_IDX(1, b)], ssab = SS[SS_IDX(2, b)];
        f1 = NS_F * sqrtf(DS_F / (ssa + 1e-5f));
        f2 = NS_F * sqrtf(DS_F / (ssb + 1e-5f));
        const float ssc = f1 * f1 * ssa + 2.f * f1 * f2 * ssab + f2 * f2 * ssb;
        f3 = NS_F * sqrtf(DS_F / (ssc + 1e-5f));
    }
#pragma unroll
    for (int j = 0; j < 4; ++j) {
        const int s = s0 + ty + j * 8;
        const size_t o = ((size_t)b * SEQ + s) * DM + d0 + tx;
        float v;
        if (mode == 0) v = f3 * Tin[o];
        else {
            const float x = Xin[o];
            v = f3 * (f1 * x * mv[(size_t)b * SEQ + s] + f2 * Tin[o]);
        }
        if (writeX) Xout[o] = v;
        tile[ty + j * 8][tx] = v;
    }
    __syncthreads();
#pragma unroll
    for (int j = 0; j < 4; ++j) {
        const int d = d0 + ty + j * 8;
        const int s = s0 + tx;
        const float v = tile[tx][ty + j * 8];
        const size_t o = ((size_t)b * DM + d) * SEQ + s;
        if (XTb) XTb[o] = f2bf(v);
        else XTf[o] = v;
    }
}

extern "C" void kernel_launch(void* const* d_in, const int* in_sizes, int n_in,
                              void* d_out, int out_size, void* d_ws, size_t ws_size,
                              hipStream_t stream) {
    const float* train_feat = (const float*)d_in[0];
    const float* test_feat  = (const float*)d_in[1];
    const float* label      = (const float*)d_in[2];
    const float* WKs        = (const float*)d_in[3];
    const float* bKs        = (const float*)d_in[4];
    const float* WKc        = (const float*)d_in[5];
    const float* bKc        = (const float*)d_in[6];
    float* out = (float*)d_out;
    float* w = (float*)d_ws;

    const size_t SBD = (size_t)NB * SEQ * DM;   // 8,388,608
    const size_t SBK = (size_t)NB * SEQ * KD;   // 2,097,152

    float* X = w;                                          // SBD f32
    float* T = X + SBD;                                    // SBD f32
    unsigned short* XTd   = (unsigned short*)(T + SBD);    // SBD bf16
    unsigned short* MEMT  = XTd + SBD;                     // SBD bf16
    unsigned short* MEMLT = MEMT + SBD;                    // SBD bf16
    unsigned short* W1h   = MEMLT + SBD;                   // SBK bf16
    unsigned short* W1l   = W1h + SBK;
    unsigned short* WKMh  = W1l + SBK;
    unsigned short* WKMl  = WKMh + SBK;
    float* MVEC = (float*)(WKMl + SBK);                    // NB*SEQ f32
    float* SS   = MVEC + (size_t)NB * SEQ;                 // SS_FLOATS f32
    float* AFF  = SS + SS_FLOATS;                          // cap*SEQ*SEQ f32

    const size_t fixed = (size_t)(AFF - w);
    const size_t per = (size_t)SEQ * SEQ + (size_t)SEQ * SEQ / 2;  // AFF f32 + P bf16
    const size_t wsf = ws_size / 4;
    int cap = 1;
    if (wsf > fixed) {
        size_t c = (wsf - fixed) / per;
        if (c < 1) c = 1;
        if (c > NB) c = NB;
        cap = (int)c;
    }
    unsigned short* Pbuf = (unsigned short*)(AFF + (size_t)cap * SEQ * SEQ);

    const dim3 gT_in(DM / 32, SEQ / 32, NB), bT(32, 8);
    const dim3 gFin(SEQ / 32, DM / 32, NB);

    auto attn = [&](const unsigned short* Qh, const unsigned short* Ql,
                    const unsigned short* Kh, const unsigned short* Kl,
                    const unsigned short* VT, const float* labelp, float* mvp,
                    const float* Xres, int pvmode) {
        for (int b0 = 0; b0 < NB; b0 += cap) {
            const int nb = (NB - b0 < cap) ? NB - b0 : cap;
            k_qk<<<dim3(8, 8, nb), 256, 0, stream>>>(Qh, Ql, Kh, Kl, AFF, b0);
            k_softmax<<<dim3(SEQ, nb), 256, 0, stream>>>(AFF, Pbuf, labelp, mvp, b0);
            k_pv<<<dim3(4, 8, nb), 256, 0, stream>>>(Pbuf, VT, Xres, mvp, T, SS, b0, pvmode);
        }
    };

    // ---------------- encoder ----------------
    k_transpose_in<<<gT_in, bT, 0, stream>>>(train_feat, X);
    k_cast<<<SBD / 8 / 256, 256, 0, stream>>>(train_feat, MEMT);
    for (int l = 0; l < 2; ++l) {
        k_proj<<<NB * SEQ / 8, 128, 0, stream>>>(X, WKs, bKs, W1h, W1l);
        k_zero<<<1, 256, 0, stream>>>(SS);
        attn(W1h, W1l, W1h, W1l, MEMT, nullptr, nullptr, X, 1);
        k_finish<<<gFin, bT, 0, stream>>>(nullptr, T, nullptr, SS, X, MEMT, nullptr, 0, 1);
    }
    k_proj<<<NB * SEQ / 8, 128, 0, stream>>>(X, WKc, bKc, WKMh, WKMl);
    k_mklabel<<<dim3(DM * SEQ / 8 / 256, NB), 256, 0, stream>>>(MEMT, label, MEMLT);

    // ---------------- decoder (x2) ----------------
    auto decoder = [&](const float* feat, float* outp) {
        k_transpose_in<<<gT_in, bT, 0, stream>>>(feat, X);
        k_cast<<<SBD / 8 / 256, 256, 0, stream>>>(feat, XTd);
        for (int l = 0; l < 2; ++l) {
            // self-attn + inorm
            k_proj<<<NB * SEQ / 8, 128, 0, stream>>>(X, WKs, bKs, W1h, W1l);
            k_zero<<<1, 256, 0, stream>>>(SS);
            attn(W1h, W1l, W1h, W1l, XTd, nullptr, nullptr, X, 1);
            k_finish<<<gFin, bT, 0, stream>>>(nullptr, T, nullptr, SS, X, XTd, nullptr, 0, 1);
            // cross-attn fused with reduce3: T = x + t3; SS[0..2] = ssa/ssb/ssab
            k_proj<<<NB * SEQ / 8, 128, 0, stream>>>(X, WKc, bKc, W1h, W1l);
            k_zero<<<1, 256, 0, stream>>>(SS);
            attn(W1h, W1l, WKMh, WKMl, MEMLT, label, MVEC, X, 2);
            // fused triple instance-norm finish
            if (l == 0)
                k_finish<<<gFin, bT, 0, stream>>>(X, T, MVEC, SS, X, XTd, nullptr, 1, 1);
            else
                k_finish<<<gFin, bT, 0, stream>>>(X, T, MVEC, SS, X, nullptr, outp, 1, 0);
        }
    };
    decoder(train_feat, out);
    decoder(test_feat, out + SBD);
}

// Round 4
// 1724.496 us; speedup vs baseline: 3.8210x; 1.0899x over previous
//
#include <hip/hip_runtime.h>
#include <math.h>

#define NB 16
#define SEQ 1024
#define DM 512
#define KD 128
#define TEMP_F 30.0f
#define NS_F 0.011048543456039805f   // sqrt(1/8192)
#define DS_F 524288.0f               // D*H*W = 512*1024

// SS: per-stage slabs; within a stage, one cache line per counter: SS[stage*768 + (grp*NB+b)*16]
#define SS_IDX(grp, b) (((grp) * NB + (b)) * 16)
#define SS_STRIDE 768
#define SS_STAGES 12
#define SS_FLOATS (SS_STRIDE * SS_STAGES)

typedef short bf16x8 __attribute__((ext_vector_type(8)));
typedef float f32x4 __attribute__((ext_vector_type(4)));
typedef unsigned short us4 __attribute__((ext_vector_type(4)));
typedef unsigned short us8 __attribute__((ext_vector_type(8)));

__device__ __forceinline__ unsigned short f2bf(float x) {
    union { float f; unsigned u; } v; v.f = x;
    unsigned r = v.u + 0x7fffu + ((v.u >> 16) & 1u);
    return (unsigned short)(r >> 16);
}
__device__ __forceinline__ float bf2f(unsigned short h) {
    union { unsigned u; float f; } v; v.u = ((unsigned)h) << 16;
    return v.f;
}

// global -> LDS async 16B/lane. lds dst must be wave-uniform base (+lane*16 implicit).
#define GLL16(gp, lp) __builtin_amdgcn_global_load_lds( \
    (__attribute__((address_space(1))) void*)(unsigned long long)(gp), \
    (__attribute__((address_space(3))) void*)(unsigned)(unsigned long long)(lp), 16, 0, 0)

// ---------------- transpose in: src [B][D][S] -> dst [B][S][D] f32 (+ bf16 copy of src) ----------------
__global__ __launch_bounds__(256) void k_transpose_in(const float* __restrict__ src,
                                                      float* __restrict__ dst,
                                                      unsigned short* __restrict__ dstT) {
    __shared__ float tile[32][33];
    const int b = blockIdx.z;
    const int d0 = blockIdx.x * 32;
    const int s0 = blockIdx.y * 32;
    const int tx = threadIdx.x, ty = threadIdx.y;  // 32x8
    const float* p = src + (size_t)b * DM * SEQ;
    float* q = dst + (size_t)b * SEQ * DM;
    unsigned short* pt = dstT ? dstT + (size_t)b * DM * SEQ : nullptr;
#pragma unroll
    for (int j = 0; j < 32; j += 8) {
        const size_t o = (size_t)(d0 + ty + j) * SEQ + s0 + tx;
        const float v = p[o];
        tile[ty + j][tx] = v;
        if (pt) pt[o] = f2bf(v);
    }
    __syncthreads();
#pragma unroll
    for (int j = 0; j < 32; j += 8)
        q[(size_t)(s0 + ty + j) * DM + d0 + tx] = tile[tx][ty + j];
}

// ---------------- MEMLT[b][d][s] = MEMT[b][d][s] * label[b][s] ----------------
__global__ __launch_bounds__(256) void k_mklabel(const unsigned short* __restrict__ MT,
                                                 const float* __restrict__ label,
                                                 unsigned short* __restrict__ ML) {
    const int b = blockIdx.y;
    const size_t off = ((size_t)blockIdx.x * 256 + threadIdx.x) * 8;
    const int s = (int)(off & (SEQ - 1));
    const size_t o = (size_t)b * DM * SEQ + off;
    us8 v = *(const us8*)(MT + o);
    const float4 l0 = *(const float4*)(label + (size_t)b * SEQ + s);
    const float4 l1 = *(const float4*)(label + (size_t)b * SEQ + s + 4);
    us8 r;
    r[0] = f2bf(bf2f(v[0]) * l0.x); r[1] = f2bf(bf2f(v[1]) * l0.y);
    r[2] = f2bf(bf2f(v[2]) * l0.z); r[3] = f2bf(bf2f(v[3]) * l0.w);
    r[4] = f2bf(bf2f(v[4]) * l1.x); r[5] = f2bf(bf2f(v[5]) * l1.y);
    r[6] = f2bf(bf2f(v[6]) * l1.z); r[7] = f2bf(bf2f(v[7]) * l1.w);
    *(us8*)(ML + o) = r;
}

// ---------------- weight split: WK [DM][KD] f32 -> WhT/WlT [KD][DM] bf16 ----------------
__global__ __launch_bounds__(256) void k_wsplit(const float* __restrict__ WK,
                                                unsigned short* __restrict__ WhT,
                                                unsigned short* __restrict__ WlT) {
    const int k = blockIdx.x;  // 0..KD
    for (int d = threadIdx.x; d < DM; d += 256) {
        const float v = WK[(size_t)d * KD + k];
        const unsigned short h = f2bf(v);
        WhT[(size_t)k * DM + d] = h;
        WlT[(size_t)k * DM + d] = f2bf(v - bf2f(h));
    }
}

// ---------------- projection MFMA: Wout[row][k] = l2norm(X[row]@WK + bK), bf16 hi/lo ----------------
// 64 rows x 128 cols per block, 4 waves (16 rows each). A from global f32 (converted to
// hi/lo in-register), B = WhT/WlT bf16 from global (L2-hot). 3-term hi/lo MFMA.
__global__ __launch_bounds__(256) void k_proj(const float* __restrict__ Xp,
                                              const unsigned short* __restrict__ WhT,
                                              const unsigned short* __restrict__ WlT,
                                              const float* __restrict__ bK,
                                              unsigned short* __restrict__ Wh,
                                              unsigned short* __restrict__ Wl) {
    const int row0 = blockIdx.x * 64;
    const int tid = threadIdx.x, w = tid >> 6, l = tid & 63;
    const int lr = l & 15, lk = (l >> 4) * 8;
    const int arow = row0 + w * 16 + lr;
    f32x4 acc[8] = {};
#pragma unroll 2
    for (int k0 = 0; k0 < DM; k0 += 32) {
        const float* ap = Xp + (size_t)arow * DM + k0 + lk;
        const float4 a0 = *(const float4*)ap;
        const float4 a1 = *(const float4*)(ap + 4);
        const float av[8] = {a0.x, a0.y, a0.z, a0.w, a1.x, a1.y, a1.z, a1.w};
        bf16x8 ah, al;
#pragma unroll
        for (int i = 0; i < 8; ++i) {
            const unsigned short h = f2bf(av[i]);
            ah[i] = (short)h;
            al[i] = (short)f2bf(av[i] - bf2f(h));
        }
#pragma unroll
        for (int fn = 0; fn < 8; ++fn) {
            const size_t bo = (size_t)(fn * 16 + lr) * DM + k0 + lk;
            const bf16x8 bh = *(const bf16x8*)(WhT + bo);
            const bf16x8 bl = *(const bf16x8*)(WlT + bo);
            acc[fn] = __builtin_amdgcn_mfma_f32_16x16x32_bf16(ah, bh, acc[fn], 0, 0, 0);
            acc[fn] = __builtin_amdgcn_mfma_f32_16x16x32_bf16(ah, bl, acc[fn], 0, 0, 0);
            acc[fn] = __builtin_amdgcn_mfma_f32_16x16x32_bf16(al, bh, acc[fn], 0, 0, 0);
        }
    }
    const int er = l & 15, eq = (l >> 4) * 4;
    float bkv[8];
#pragma unroll
    for (int fn = 0; fn < 8; ++fn) bkv[fn] = bK[fn * 16 + er];
#pragma unroll
    for (int r = 0; r < 4; ++r) {
        float v[8];
        float ss = 0.f;
#pragma unroll
        for (int fn = 0; fn < 8; ++fn) {
            v[fn] = acc[fn][r] + bkv[fn];
            ss += v[fn] * v[fn];
        }
#pragma unroll
        for (int o = 8; o > 0; o >>= 1) ss += __shfl_xor(ss, o, 64);
        const float invn = 1.0f / fmaxf(sqrtf(ss), 1e-12f);
        const size_t ro = (size_t)(row0 + w * 16 + eq + r) * KD;
#pragma unroll
        for (int fn = 0; fn < 8; ++fn) {
            const float ov = v[fn] * invn;
            const unsigned short h = f2bf(ov);
            Wh[ro + fn * 16 + er] = h;
            Wl[ro + fn * 16 + er] = f2bf(ov - bf2f(h));
        }
    }
}

// ---------------- QK^T MFMA (bf16 hi/lo x3): Aff = TEMP * Wq . Wk^T ----------------
__global__ __launch_bounds__(256) void k_qk(const unsigned short* __restrict__ Qh,
                                            const unsigned short* __restrict__ Ql,
                                            const unsigned short* __restrict__ Kh,
                                            const unsigned short* __restrict__ Kl,
                                            float* __restrict__ Aff, int b0) {
    const int bz = blockIdx.z, b = b0 + bz;
    const int i0 = blockIdx.y * 128, j0 = blockIdx.x * 128;
    const size_t ob = (size_t)b * SEQ * KD;
    const unsigned short* Ah_g = Qh + ob;
    const unsigned short* Al_g = Ql + ob;
    const unsigned short* Bh_g = Kh + ob;
    const unsigned short* Bl_g = Kl + ob;
    __shared__ short Ah[128 * 32], Al[128 * 32], Bh[128 * 32], Bl[128 * 32];
    const int tid = threadIdx.x, w = tid >> 6, l = tid & 63;
    const int wm = (w >> 1) * 64, wn = (w & 1) * 64;
    const int srow = l >> 2, scol = (l & 3) * 8;
    f32x4 acc[4][4] = {};
    for (int k0 = 0; k0 < KD; k0 += 32) {
#pragma unroll
        for (int cc = 0; cc < 2; ++cc) {
            const int c = 2 * w + cc;
            const size_t ra = (size_t)(i0 + c * 16 + srow) * KD + k0 + scol;
            const size_t rb = (size_t)(j0 + c * 16 + srow) * KD + k0 + scol;
            GLL16(Ah_g + ra, &Ah[c * 512]);
            GLL16(Al_g + ra, &Al[c * 512]);
            GLL16(Bh_g + rb, &Bh[c * 512]);
            GLL16(Bl_g + rb, &Bl[c * 512]);
        }
        __syncthreads();
        const int lr = l & 15, lk = (l >> 4) * 8;
        bf16x8 ah[4], al[4], bh[4], bl[4];
#pragma unroll
        for (int f = 0; f < 4; ++f) {
            ah[f] = *(const bf16x8*)&Ah[(wm + f * 16 + lr) * 32 + lk];
            al[f] = *(const bf16x8*)&Al[(wm + f * 16 + lr) * 32 + lk];
            bh[f] = *(const bf16x8*)&Bh[(wn + f * 16 + lr) * 32 + lk];
            bl[f] = *(const bf16x8*)&Bl[(wn + f * 16 + lr) * 32 + lk];
        }
#pragma unroll
        for (int fm = 0; fm < 4; ++fm)
#pragma unroll
            for (int fn = 0; fn < 4; ++fn) {
                acc[fm][fn] = __builtin_amdgcn_mfma_f32_16x16x32_bf16(ah[fm], bh[fn], acc[fm][fn], 0, 0, 0);
                acc[fm][fn] = __builtin_amdgcn_mfma_f32_16x16x32_bf16(ah[fm], bl[fn], acc[fm][fn], 0, 0, 0);
                acc[fm][fn] = __builtin_amdgcn_mfma_f32_16x16x32_bf16(al[fm], bh[fn], acc[fm][fn], 0, 0, 0);
            }
        __syncthreads();
    }
    float* Cb = Aff + (size_t)bz * SEQ * SEQ;
    const int er = l & 15, eq = (l >> 4) * 4;
#pragma unroll
    for (int fm = 0; fm < 4; ++fm)
#pragma unroll
        for (int fn = 0; fn < 4; ++fn)
#pragma unroll
            for (int r = 0; r < 4; ++r)
                Cb[(size_t)(i0 + wm + fm * 16 + eq + r) * SEQ + j0 + wn + fn * 16 + er] =
                    TEMP_F * acc[fm][fn][r];
}

// ---------------- softmax rows -> P bf16 (normalized), optional mvec ----------------
__global__ __launch_bounds__(256) void k_softmax(const float* __restrict__ Aff,
                                                 unsigned short* __restrict__ P,
                                                 const float* __restrict__ labelp,
                                                 float* __restrict__ mvec, int b0) {
    const int bz = blockIdx.y, b = b0 + bz;
    const int q = blockIdx.x;
    const float* row = Aff + ((size_t)bz * SEQ + q) * SEQ;
    unsigned short* prow = P + ((size_t)bz * SEQ + q) * SEQ;
    const int t = threadIdx.x;
    __shared__ float red[256];
    float4 v = ((const float4*)row)[t];
    red[t] = fmaxf(fmaxf(v.x, v.y), fmaxf(v.z, v.w));
    __syncthreads();
#pragma unroll
    for (int o = 128; o > 0; o >>= 1) { if (t < o) red[t] = fmaxf(red[t], red[t + o]); __syncthreads(); }
    const float mx = red[0];
    __syncthreads();
    float e0 = __expf(v.x - mx), e1 = __expf(v.y - mx), e2 = __expf(v.z - mx), e3 = __expf(v.w - mx);
    red[t] = e0 + e1 + e2 + e3;
    __syncthreads();
#pragma unroll
    for (int o = 128; o > 0; o >>= 1) { if (t < o) red[t] += red[t + o]; __syncthreads(); }
    const float inv = 1.0f / red[0];
    e0 *= inv; e1 *= inv; e2 *= inv; e3 *= inv;
    us4 pw; pw.x = f2bf(e0); pw.y = f2bf(e1); pw.z = f2bf(e2); pw.w = f2bf(e3);
    ((us4*)prow)[t] = pw;
    if (labelp) {
        __syncthreads();
        const float4 lb = ((const float4*)(labelp + (size_t)b * SEQ))[t];
        red[t] = e0 * lb.x + e1 * lb.y + e2 * lb.z + e3 * lb.w;
        __syncthreads();
#pragma unroll
        for (int o = 128; o > 0; o >>= 1) { if (t < o) red[t] += red[t + o]; __syncthreads(); }
        if (t == 0) mvec[(size_t)b * SEQ + q] = red[0];
    }
}

// ---------------- PV MFMA: acc = P x VT^T ----------------
// mode 1: Cout = acc + X, ssq -> SS[0][b]                       (self-attn)
// mode 2: Cout = acc + X (=x+t3); sa=(x*m)^2, sb=(x+t3)^2, sab -> SS[0..2][b]  (cross)
__global__ __launch_bounds__(256) void k_pv(const unsigned short* __restrict__ P,
                                            const unsigned short* __restrict__ VT,
                                            const float* __restrict__ Xres,
                                            const float* __restrict__ mvp,
                                            float* __restrict__ Cout,
                                            float* __restrict__ SS, int b0, int mode) {
    const int bz = blockIdx.z, b = b0 + bz;
    const int i0 = blockIdx.y * 128, j0 = blockIdx.x * 128;
    const unsigned short* Pb = P + (size_t)bz * SEQ * SEQ;
    const unsigned short* Vb = VT + (size_t)b * DM * SEQ;
    __shared__ short Pa[128 * 64], Vv[128 * 64];
    __shared__ float sh_mv[128];
    const int tid = threadIdx.x, w = tid >> 6, l = tid & 63;
    const int wm = (w >> 1) * 64, wn = (w & 1) * 64;
    const int srow = l >> 3, scol = (l & 7) * 8;
    f32x4 acc[4][4] = {};
    for (int k0 = 0; k0 < SEQ; k0 += 64) {
#pragma unroll
        for (int cc = 0; cc < 4; ++cc) {
            const int c = 4 * w + cc;
            GLL16(Pb + (size_t)(i0 + c * 8 + srow) * SEQ + k0 + scol, &Pa[c * 512]);
            GLL16(Vb + (size_t)(j0 + c * 8 + srow) * SEQ + k0 + scol, &Vv[c * 512]);
        }
        __syncthreads();
        const int lr = l & 15, lk = (l >> 4) * 8;
#pragma unroll
        for (int kc = 0; kc < 2; ++kc) {
            bf16x8 a[4], bb[4];
#pragma unroll
            for (int f = 0; f < 4; ++f) {
                a[f] = *(const bf16x8*)&Pa[(wm + f * 16 + lr) * 64 + kc * 32 + lk];
                bb[f] = *(const bf16x8*)&Vv[(wn + f * 16 + lr) * 64 + kc * 32 + lk];
            }
#pragma unroll
            for (int fm = 0; fm < 4; ++fm)
#pragma unroll
                for (int fn = 0; fn < 4; ++fn)
                    acc[fm][fn] = __builtin_amdgcn_mfma_f32_16x16x32_bf16(a[fm], bb[fn], acc[fm][fn], 0, 0, 0);
        }
        __syncthreads();
    }
    if (mode == 2) {
        if (tid < 128) sh_mv[tid] = mvp[(size_t)b * SEQ + i0 + tid];
        __syncthreads();
    }
    float sa = 0.f, sb = 0.f, sab = 0.f;
    const int er = l & 15, eq = (l >> 4) * 4;
#pragma unroll
    for (int fm = 0; fm < 4; ++fm)
#pragma unroll
        for (int fn = 0; fn < 4; ++fn)
#pragma unroll
            for (int r = 0; r < 4; ++r) {
                const int lrow = wm + fm * 16 + eq + r;
                const int col = j0 + wn + fn * 16 + er;
                float v = acc[fm][fn][r];
                const size_t o = ((size_t)b * SEQ + i0 + lrow) * DM + col;
                if (mode >= 1) {
                    const float x = Xres[o];
                    v += x;
                    sb += v * v;
                    if (mode == 2) {
                        const float a = x * sh_mv[lrow];
                        sa += a * a;
                        sab += a * v;
                    }
                }
                Cout[o] = v;
            }
    if (mode >= 1) {
#pragma unroll
        for (int off = 32; off > 0; off >>= 1) {
            sb += __shfl_xor(sb, off, 64);
            if (mode == 2) { sa += __shfl_xor(sa, off, 64); sab += __shfl_xor(sab, off, 64); }
        }
        __shared__ float ps[3][4];
        if (l == 0) { ps[0][w] = sb; ps[1][w] = sa; ps[2][w] = sab; }
        __syncthreads();
        if (tid == 0) {
            if (mode == 1) {
                atomicAdd(&SS[SS_IDX(0, b)], ps[0][0] + ps[0][1] + ps[0][2] + ps[0][3]);
            } else {
                atomicAdd(&SS[SS_IDX(0, b)], ps[1][0] + ps[1][1] + ps[1][2] + ps[1][3]);
                atomicAdd(&SS[SS_IDX(1, b)], ps[0][0] + ps[0][1] + ps[0][2] + ps[0][3]);
                atomicAdd(&SS[SS_IDX(2, b)], ps[2][0] + ps[2][1] + ps[2][2] + ps[2][3]);
            }
        }
    }
}

// ---------------- zero all SS stages (once per launch) ----------------
__global__ void k_zero(float* __restrict__ SSb) {
    const int i = blockIdx.x * 256 + threadIdx.x;
    if (i < SS_FLOATS) SSb[i] = 0.0f;
}

// ---------------- finish: compute v, write X [S][D] f32 + transposed bf16/f32 ----------------
// mode 0: v = f*T ; mode 1: v = f3*(f1*x*mv + f2*T)  (T already holds x+t3)
__global__ __launch_bounds__(256) void k_finish(const float* __restrict__ Xin,
                                                const float* __restrict__ Tin,
                                                const float* __restrict__ mv,
                                                const float* __restrict__ SS,
                                                float* __restrict__ Xout,
                                                unsigned short* __restrict__ XTb,
                                                float* __restrict__ XTf,
                                                int mode, int writeX) {
    const int b = blockIdx.z;
    const int s0 = blockIdx.x * 32, d0 = blockIdx.y * 32;
    const int tx = threadIdx.x, ty = threadIdx.y;
    __shared__ float tile[32][33];
    float f1 = 0.f, f2 = 0.f, f3;
    if (mode == 0) {
        f3 = NS_F * sqrtf(DS_F / (SS[SS_IDX(0, b)] + 1e-5f));
    } else {
        const float ssa = SS[SS_IDX(0, b)], ssb = SS[SS_IDX(1, b)], ssab = SS[SS_IDX(2, b)];
        f1 = NS_F * sqrtf(DS_F / (ssa + 1e-5f));
        f2 = NS_F * sqrtf(DS_F / (ssb + 1e-5f));
        const float ssc = f1 * f1 * ssa + 2.f * f1 * f2 * ssab + f2 * f2 * ssb;
        f3 = NS_F * sqrtf(DS_F / (ssc + 1e-5f));
    }
#pragma unroll
    for (int j = 0; j < 4; ++j) {
        const int s = s0 + ty + j * 8;
        const size_t o = ((size_t)b * SEQ + s) * DM + d0 + tx;
        float v;
        if (mode == 0) v = f3 * Tin[o];
        else {
            const float x = Xin[o];
            v = f3 * (f1 * x * mv[(size_t)b * SEQ + s] + f2 * Tin[o]);
        }
        if (writeX) Xout[o] = v;
        tile[ty + j * 8][tx] = v;
    }
    __syncthreads();
#pragma unroll
    for (int j = 0; j < 4; ++j) {
        const int d = d0 + ty + j * 8;
        const int s = s0 + tx;
        const float v = tile[tx][ty + j * 8];
        const size_t o = ((size_t)b * DM + d) * SEQ + s;
        if (XTb) XTb[o] = f2bf(v);
        else XTf[o] = v;
    }
}

extern "C" void kernel_launch(void* const* d_in, const int* in_sizes, int n_in,
                              void* d_out, int out_size, void* d_ws, size_t ws_size,
                              hipStream_t stream) {
    const float* train_feat = (const float*)d_in[0];
    const float* test_feat  = (const float*)d_in[1];
    const float* label      = (const float*)d_in[2];
    const float* WKs        = (const float*)d_in[3];
    const float* bKs        = (const float*)d_in[4];
    const float* WKc        = (const float*)d_in[5];
    const float* bKc        = (const float*)d_in[6];
    float* out = (float*)d_out;
    float* w = (float*)d_ws;

    const size_t SBD = (size_t)NB * SEQ * DM;   // 8,388,608
    const size_t SBK = (size_t)NB * SEQ * KD;   // 2,097,152
    const size_t WSZ = (size_t)DM * KD;         // 65,536

    float* X = w;                                          // SBD f32
    float* T = X + SBD;                                    // SBD f32
    unsigned short* XTd   = (unsigned short*)(T + SBD);    // SBD bf16
    unsigned short* MEMT  = XTd + SBD;                     // SBD bf16
    unsigned short* MEMLT = MEMT + SBD;                    // SBD bf16
    unsigned short* W1h   = MEMLT + SBD;                   // SBK bf16
    unsigned short* W1l   = W1h + SBK;
    unsigned short* WKMh  = W1l + SBK;
    unsigned short* WKMl  = WKMh + SBK;
    unsigned short* WsTh  = WKMl + SBK;                    // WSZ bf16 (self W^T hi)
    unsigned short* WsTl  = WsTh + WSZ;
    unsigned short* WcTh  = WsTl + WSZ;
    unsigned short* WcTl  = WcTh + WSZ;
    float* MVEC = (float*)(WcTl + WSZ);                    // NB*SEQ f32
    float* SS   = MVEC + (size_t)NB * SEQ;                 // SS_FLOATS f32
    float* AFF  = SS + SS_FLOATS;                          // cap*SEQ*SEQ f32

    const size_t fixed = (size_t)(AFF - w);
    const size_t per = (size_t)SEQ * SEQ + (size_t)SEQ * SEQ / 2;  // AFF f32 + P bf16
    const size_t wsf = ws_size / 4;
    int cap = 1;
    if (wsf > fixed) {
        size_t c = (wsf - fixed) / per;
        if (c < 1) c = 1;
        if (c > NB) c = NB;
        cap = (int)c;
    }
    unsigned short* Pbuf = (unsigned short*)(AFF + (size_t)cap * SEQ * SEQ);

    const dim3 gT_in(DM / 32, SEQ / 32, NB), bT(32, 8);
    const dim3 gFin(SEQ / 32, DM / 32, NB);

    int stage = 0;
    auto nextSS = [&]() { return SS + (size_t)(stage++) * SS_STRIDE; };

    auto attn = [&](const unsigned short* Qh, const unsigned short* Ql,
                    const unsigned short* Kh, const unsigned short* Kl,
                    const unsigned short* VT, const float* labelp, float* mvp,
                    const float* Xres, int pvmode, float* SSst) {
        for (int b0 = 0; b0 < NB; b0 += cap) {
            const int nb = (NB - b0 < cap) ? NB - b0 : cap;
            k_qk<<<dim3(8, 8, nb), 256, 0, stream>>>(Qh, Ql, Kh, Kl, AFF, b0);
            k_softmax<<<dim3(SEQ, nb), 256, 0, stream>>>(AFF, Pbuf, labelp, mvp, b0);
            k_pv<<<dim3(4, 8, nb), 256, 0, stream>>>(Pbuf, VT, Xres, mvp, T, SSst, b0, pvmode);
        }
    };

    // ---------------- setup ----------------
    k_zero<<<(SS_FLOATS + 255) / 256, 256, 0, stream>>>(SS);
    k_wsplit<<<KD, 256, 0, stream>>>(WKs, WsTh, WsTl);
    k_wsplit<<<KD, 256, 0, stream>>>(WKc, WcTh, WcTl);

    // ---------------- encoder ----------------
    k_transpose_in<<<gT_in, bT, 0, stream>>>(train_feat, X, MEMT);
    for (int l = 0; l < 2; ++l) {
        float* SSst = nextSS();
        k_proj<<<NB * SEQ / 64, 256, 0, stream>>>(X, WsTh, WsTl, bKs, W1h, W1l);
        attn(W1h, W1l, W1h, W1l, MEMT, nullptr, nullptr, X, 1, SSst);
        k_finish<<<gFin, bT, 0, stream>>>(nullptr, T, nullptr, SSst, X, MEMT, nullptr, 0, 1);
    }
    k_proj<<<NB * SEQ / 64, 256, 0, stream>>>(X, WcTh, WcTl, bKc, WKMh, WKMl);
    k_mklabel<<<dim3(DM * SEQ / 8 / 256, NB), 256, 0, stream>>>(MEMT, label, MEMLT);

    // ---------------- decoder (x2) ----------------
    auto decoder = [&](const float* feat, float* outp) {
        k_transpose_in<<<gT_in, bT, 0, stream>>>(feat, X, XTd);
        for (int l = 0; l < 2; ++l) {
            // self-attn + inorm
            float* SSst = nextSS();
            k_proj<<<NB * SEQ / 64, 256, 0, stream>>>(X, WsTh, WsTl, bKs, W1h, W1l);
            attn(W1h, W1l, W1h, W1l, XTd, nullptr, nullptr, X, 1, SSst);
            k_finish<<<gFin, bT, 0, stream>>>(nullptr, T, nullptr, SSst, X, XTd, nullptr, 0, 1);
            // cross-attn fused with reduce3: T = x + t3; SS[0..2] = ssa/ssb/ssab
            float* SSst2 = nextSS();
            k_proj<<<NB * SEQ / 64, 256, 0, stream>>>(X, WcTh, WcTl, bKc, W1h, W1l);
            attn(W1h, W1l, WKMh, WKMl, MEMLT, label, MVEC, X, 2, SSst2);
            // fused triple instance-norm finish
            if (l == 0)
                k_finish<<<gFin, bT, 0, stream>>>(X, T, MVEC, SSst2, X, XTd, nullptr, 1, 1);
            else
                k_finish<<<gFin, bT, 0, stream>>>(X, T, MVEC, SSst2, X, nullptr, outp, 1, 0);
        }
    };
    decoder(train_feat, out);
    decoder(test_feat, out + SBD);
}

// Round 5
// 1403.753 us; speedup vs baseline: 4.6940x; 1.2285x over previous
//
#include <hip/hip_runtime.h>
#include <math.h>

#define NB 16
#define SEQ 1024
#define DM 512
#define KD 128
#define TEMP_F 30.0f
#define NS_F 0.011048543456039805f   // sqrt(1/8192)
#define DS_F 524288.0f               // D*H*W = 512*1024

// SS: per-stage slabs; within a stage, one cache line per counter
#define SS_IDX(grp, b) (((grp) * NB + (b)) * 16)
#define SS_STRIDE 768
#define SS_STAGES 12
#define SS_FLOATS (SS_STRIDE * SS_STAGES)

typedef short bf16x8 __attribute__((ext_vector_type(8)));
typedef float f32x4 __attribute__((ext_vector_type(4)));
typedef unsigned short us;
typedef unsigned short us4 __attribute__((ext_vector_type(4)));
typedef unsigned short us8 __attribute__((ext_vector_type(8)));

__device__ __forceinline__ us f2bf(float x) {
    union { float f; unsigned u; } v; v.f = x;
    unsigned r = v.u + 0x7fffu + ((v.u >> 16) & 1u);
    return (us)(r >> 16);
}
__device__ __forceinline__ float bf2f(us h) {
    union { unsigned u; float f; } v; v.u = ((unsigned)h) << 16;
    return v.f;
}

// global -> LDS async 16B/lane. lds dst = wave-uniform base + lane*16 implicit.
#define GLL16(gp, lp) __builtin_amdgcn_global_load_lds( \
    (__attribute__((address_space(1))) void*)(unsigned long long)(gp), \
    (__attribute__((address_space(3))) void*)(unsigned)(unsigned long long)(lp), 16, 0, 0)

// Swizzled LDS tile convention for [R][64] bf16 tiles staged via GLL16:
//   stage: lane l of chunk c loads global (row = base + c*8 + (l>>3),
//          colchunk = (l&7) ^ (l>>3)) into linear LDS (chunk base + l*16B).
//   read:  element (row, kk) lives at LDS elem  row*64 + (kk ^ ((row&7)<<3)).

// ---------------- transpose in: src [B][D][S] f32 -> XC [B][S][1024] bf16 hi|lo + XT [B][D][S] bf16 ----------------
__global__ __launch_bounds__(256) void k_transpose_in(const float* __restrict__ src,
                                                      us* __restrict__ XC,
                                                      us* __restrict__ XT) {
    __shared__ float tile[32][33];
    const int b = blockIdx.z;
    const int d0 = blockIdx.x * 32;
    const int s0 = blockIdx.y * 32;
    const int tx = threadIdx.x, ty = threadIdx.y;  // 32x8
    const float* p = src + (size_t)b * DM * SEQ;
    us* pt = XT + (size_t)b * DM * SEQ;
    us* pc = XC + (size_t)b * SEQ * 1024;
#pragma unroll
    for (int j = 0; j < 32; j += 8) {
        const size_t o = (size_t)(d0 + ty + j) * SEQ + s0 + tx;
        const float v = p[o];
        tile[ty + j][tx] = v;
        pt[o] = f2bf(v);
    }
    __syncthreads();
#pragma unroll
    for (int j = 0; j < 4; ++j) {
        const int s = s0 + ty + j * 8;
        const int d = d0 + tx;
        const float v = tile[tx][ty + j * 8];
        const us h = f2bf(v);
        pc[(size_t)s * 1024 + d] = h;
        pc[(size_t)s * 1024 + 512 + d] = f2bf(v - bf2f(h));
    }
}

// ---------------- MEMLT[b][d][s] = MEMT[b][d][s] * label[b][s] ----------------
__global__ __launch_bounds__(256) void k_mklabel(const us* __restrict__ MT,
                                                 const float* __restrict__ label,
                                                 us* __restrict__ ML) {
    const int b = blockIdx.y;
    const size_t off = ((size_t)blockIdx.x * 256 + threadIdx.x) * 8;
    const int s = (int)(off & (SEQ - 1));
    const size_t o = (size_t)b * DM * SEQ + off;
    us8 v = *(const us8*)(MT + o);
    const float4 l0 = *(const float4*)(label + (size_t)b * SEQ + s);
    const float4 l1 = *(const float4*)(label + (size_t)b * SEQ + s + 4);
    us8 r;
    r[0] = f2bf(bf2f(v[0]) * l0.x); r[1] = f2bf(bf2f(v[1]) * l0.y);
    r[2] = f2bf(bf2f(v[2]) * l0.z); r[3] = f2bf(bf2f(v[3]) * l0.w);
    r[4] = f2bf(bf2f(v[4]) * l1.x); r[5] = f2bf(bf2f(v[5]) * l1.y);
    r[6] = f2bf(bf2f(v[6]) * l1.z); r[7] = f2bf(bf2f(v[7]) * l1.w);
    *(us8*)(ML + o) = r;
}

// ---------------- weight split: WK [DM][KD] f32 -> WC [KD][1024] bf16 hi|lo ----------------
__global__ __launch_bounds__(256) void k_wsplit(const float* __restrict__ WK,
                                                us* __restrict__ WC) {
    const int k = blockIdx.x;  // 0..KD
    for (int d = threadIdx.x; d < DM; d += 256) {
        const float v = WK[(size_t)d * KD + k];
        const us h = f2bf(v);
        WC[(size_t)k * 1024 + d] = h;
        WC[(size_t)k * 1024 + 512 + d] = f2bf(v - bf2f(h));
    }
}

// ---------------- projection GEMM: W1C[row][0:128]=hi,[128:256]=lo of l2norm(X@WK+bK) ----------------
// Tile 64 rows x 128 cols, 4 waves (2m x 2n), virtual K=1536: A=[xh|xl|xh], B=[wh|wh|wl].
__global__ __launch_bounds__(256) void k_proj(const us* __restrict__ XC,
                                              const us* __restrict__ WC,
                                              const float* __restrict__ bK,
                                              us* __restrict__ Wout) {
    const int row0 = blockIdx.x * 64;
    __shared__ short As[64 * 64], Bs[128 * 64];
    __shared__ float ssp[2][64];
    const int tid = threadIdx.x, w = tid >> 6, l = tid & 63;
    const int wm = (w >> 1) * 32, wn = (w & 1) * 64;
    const int sr = l >> 3, sc = (((l & 7) ^ (l >> 3)) << 3);
    const int lr = l & 15, lk = (l >> 4) * 8;
    const int sx = (lr & 7) << 3;
    f32x4 acc[2][4] = {};
    for (int k0 = 0; k0 < 1536; k0 += 64) {
        const int ak0 = (k0 < 1024) ? k0 : k0 - 1024;
        const int bk0 = (k0 < 512) ? k0 : k0 - 512;
#pragma unroll
        for (int cc = 0; cc < 2; ++cc) {
            const int c = 2 * w + cc;
            GLL16(XC + (size_t)(row0 + c * 8 + sr) * 1024 + ak0 + sc, &As[c * 512]);
        }
#pragma unroll
        for (int cc = 0; cc < 4; ++cc) {
            const int c = 4 * w + cc;
            GLL16(WC + (size_t)(c * 8 + sr) * 1024 + bk0 + sc, &Bs[c * 512]);
        }
        __syncthreads();
#pragma unroll
        for (int kc = 0; kc < 2; ++kc) {
            const int kk = kc * 32 + lk;
            bf16x8 a[2], bb[4];
#pragma unroll
            for (int fm = 0; fm < 2; ++fm)
                a[fm] = *(const bf16x8*)&As[(wm + fm * 16 + lr) * 64 + (kk ^ sx)];
#pragma unroll
            for (int fn = 0; fn < 4; ++fn)
                bb[fn] = *(const bf16x8*)&Bs[(wn + fn * 16 + lr) * 64 + (kk ^ sx)];
#pragma unroll
            for (int fm = 0; fm < 2; ++fm)
#pragma unroll
                for (int fn = 0; fn < 4; ++fn)
                    acc[fm][fn] = __builtin_amdgcn_mfma_f32_16x16x32_bf16(a[fm], bb[fn], acc[fm][fn], 0, 0, 0);
        }
        __syncthreads();
    }
    const int er = l & 15, eq = (l >> 4) * 4;
    const int nh = w & 1;
    float bkv[4];
#pragma unroll
    for (int fn = 0; fn < 4; ++fn) bkv[fn] = bK[wn + fn * 16 + er];
    float vv[2][4][4];
#pragma unroll
    for (int fm = 0; fm < 2; ++fm)
#pragma unroll
        for (int r = 0; r < 4; ++r) {
            float ss = 0.f;
#pragma unroll
            for (int fn = 0; fn < 4; ++fn) {
                const float t = acc[fm][fn][r] + bkv[fn];
                vv[fm][fn][r] = t;
                ss += t * t;
            }
#pragma unroll
            for (int o = 8; o > 0; o >>= 1) ss += __shfl_xor(ss, o, 64);
            if (er == 0) ssp[nh][wm + fm * 16 + eq + r] = ss;
        }
    __syncthreads();
#pragma unroll
    for (int fm = 0; fm < 2; ++fm)
#pragma unroll
        for (int r = 0; r < 4; ++r) {
            const int rowloc = wm + fm * 16 + eq + r;
            const float tot = ssp[0][rowloc] + ssp[1][rowloc];
            const float invn = 1.0f / fmaxf(sqrtf(tot), 1e-12f);
            const size_t ro = (size_t)(row0 + rowloc) * 256;
#pragma unroll
            for (int fn = 0; fn < 4; ++fn) {
                const float ov = vv[fm][fn][r] * invn;
                const us h = f2bf(ov);
                Wout[ro + wn + fn * 16 + er] = h;
                Wout[ro + 128 + wn + fn * 16 + er] = f2bf(ov - bf2f(h));
            }
        }
}

// ---------------- QK^T GEMM: Aff = TEMP * q.k over virtual K=384 ([qh|ql|qh] x [kh|kh|kl]) ----------------
__global__ __launch_bounds__(256) void k_qk(const us* __restrict__ Qc,
                                            const us* __restrict__ Kc,
                                            float* __restrict__ Aff, int b0) {
    const int bz = blockIdx.z, b = b0 + bz;
    const int i0 = blockIdx.y * 128, j0 = blockIdx.x * 128;
    const us* Ab = Qc + (size_t)b * SEQ * 256;
    const us* Bb = Kc + (size_t)b * SEQ * 256;
    __shared__ short As[128 * 64], Bs[128 * 64];
    const int tid = threadIdx.x, w = tid >> 6, l = tid & 63;
    const int wm = (w >> 1) * 64, wn = (w & 1) * 64;
    const int sr = l >> 3, sc = (((l & 7) ^ (l >> 3)) << 3);
    const int lr = l & 15, lk = (l >> 4) * 8;
    const int sx = (lr & 7) << 3;
    f32x4 acc[4][4] = {};
    for (int k0 = 0; k0 < 384; k0 += 64) {
        const int ak0 = (k0 < 256) ? k0 : k0 - 256;
        const int bk0 = (k0 < 128) ? k0 : k0 - 128;
#pragma unroll
        for (int cc = 0; cc < 4; ++cc) {
            const int c = 4 * w + cc;
            GLL16(Ab + (size_t)(i0 + c * 8 + sr) * 256 + ak0 + sc, &As[c * 512]);
            GLL16(Bb + (size_t)(j0 + c * 8 + sr) * 256 + bk0 + sc, &Bs[c * 512]);
        }
        __syncthreads();
#pragma unroll
        for (int kc = 0; kc < 2; ++kc) {
            const int kk = kc * 32 + lk;
            bf16x8 a[4], bb[4];
#pragma unroll
            for (int f = 0; f < 4; ++f) {
                a[f]  = *(const bf16x8*)&As[(wm + f * 16 + lr) * 64 + (kk ^ sx)];
                bb[f] = *(const bf16x8*)&Bs[(wn + f * 16 + lr) * 64 + (kk ^ sx)];
            }
#pragma unroll
            for (int fm = 0; fm < 4; ++fm)
#pragma unroll
                for (int fn = 0; fn < 4; ++fn)
                    acc[fm][fn] = __builtin_amdgcn_mfma_f32_16x16x32_bf16(a[fm], bb[fn], acc[fm][fn], 0, 0, 0);
        }
        __syncthreads();
    }
    float* Cb = Aff + (size_t)bz * SEQ * SEQ;
    const int er = l & 15, eq = (l >> 4) * 4;
#pragma unroll
    for (int fm = 0; fm < 4; ++fm)
#pragma unroll
        for (int fn = 0; fn < 4; ++fn)
#pragma unroll
            for (int r = 0; r < 4; ++r)
                Cb[(size_t)(i0 + wm + fm * 16 + eq + r) * SEQ + j0 + wn + fn * 16 + er] =
                    TEMP_F * acc[fm][fn][r];
}

// ---------------- softmax rows -> P bf16 (normalized), optional mvec ----------------
__global__ __launch_bounds__(256) void k_softmax(const float* __restrict__ Aff,
                                                 us* __restrict__ P,
                                                 const float* __restrict__ labelp,
                                                 float* __restrict__ mvec, int b0) {
    const int bz = blockIdx.y, b = b0 + bz;
    const int q = blockIdx.x;
    const float* row = Aff + ((size_t)bz * SEQ + q) * SEQ;
    us* prow = P + ((size_t)bz * SEQ + q) * SEQ;
    const int t = threadIdx.x;
    __shared__ float red[256];
    float4 v = ((const float4*)row)[t];
    red[t] = fmaxf(fmaxf(v.x, v.y), fmaxf(v.z, v.w));
    __syncthreads();
#pragma unroll
    for (int o = 128; o > 0; o >>= 1) { if (t < o) red[t] = fmaxf(red[t], red[t + o]); __syncthreads(); }
    const float mx = red[0];
    __syncthreads();
    float e0 = __expf(v.x - mx), e1 = __expf(v.y - mx), e2 = __expf(v.z - mx), e3 = __expf(v.w - mx);
    red[t] = e0 + e1 + e2 + e3;
    __syncthreads();
#pragma unroll
    for (int o = 128; o > 0; o >>= 1) { if (t < o) red[t] += red[t + o]; __syncthreads(); }
    const float inv = 1.0f / red[0];
    e0 *= inv; e1 *= inv; e2 *= inv; e3 *= inv;
    us4 pw; pw.x = f2bf(e0); pw.y = f2bf(e1); pw.z = f2bf(e2); pw.w = f2bf(e3);
    ((us4*)prow)[t] = pw;
    if (labelp) {
        __syncthreads();
        const float4 lb = ((const float4*)(labelp + (size_t)b * SEQ))[t];
        red[t] = e0 * lb.x + e1 * lb.y + e2 * lb.z + e3 * lb.w;
        __syncthreads();
#pragma unroll
        for (int o = 128; o > 0; o >>= 1) { if (t < o) red[t] += red[t + o]; __syncthreads(); }
        if (t == 0) mvec[(size_t)b * SEQ + q] = red[0];
    }
}

// ---------------- PV GEMM: acc = P x VT^T (K=SEQ), swizzled staging ----------------
// mode 1: T = acc + x, ssq -> SS[0][b]            (self)
// mode 2: T = acc + x; sa=(x*m)^2 sb=(x+t3)^2 sab (cross)  [x reconstructed from XC hi+lo]
__global__ __launch_bounds__(256) void k_pv(const us* __restrict__ P,
                                            const us* __restrict__ VT,
                                            const us* __restrict__ XC,
                                            const float* __restrict__ mvp,
                                            float* __restrict__ Cout,
                                            float* __restrict__ SS, int b0, int mode) {
    const int bz = blockIdx.z, b = b0 + bz;
    const int i0 = blockIdx.y * 128, j0 = blockIdx.x * 128;
    const us* Pb = P + (size_t)bz * SEQ * SEQ;
    const us* Vb = VT + (size_t)b * DM * SEQ;
    __shared__ short As[128 * 64], Bs[128 * 64];
    __shared__ float sh_mv[128];
    __shared__ float ps[3][4];
    const int tid = threadIdx.x, w = tid >> 6, l = tid & 63;
    const int wm = (w >> 1) * 64, wn = (w & 1) * 64;
    const int sr = l >> 3, sc = (((l & 7) ^ (l >> 3)) << 3);
    const int lr = l & 15, lk = (l >> 4) * 8;
    const int sx = (lr & 7) << 3;
    f32x4 acc[4][4] = {};
    for (int k0 = 0; k0 < SEQ; k0 += 64) {
#pragma unroll
        for (int cc = 0; cc < 4; ++cc) {
            const int c = 4 * w + cc;
            GLL16(Pb + (size_t)(i0 + c * 8 + sr) * SEQ + k0 + sc, &As[c * 512]);
            GLL16(Vb + (size_t)(j0 + c * 8 + sr) * SEQ + k0 + sc, &Bs[c * 512]);
        }
        __syncthreads();
#pragma unroll
        for (int kc = 0; kc < 2; ++kc) {
            const int kk = kc * 32 + lk;
            bf16x8 a[4], bb[4];
#pragma unroll
            for (int f = 0; f < 4; ++f) {
                a[f]  = *(const bf16x8*)&As[(wm + f * 16 + lr) * 64 + (kk ^ sx)];
                bb[f] = *(const bf16x8*)&Bs[(wn + f * 16 + lr) * 64 + (kk ^ sx)];
            }
#pragma unroll
            for (int fm = 0; fm < 4; ++fm)
#pragma unroll
                for (int fn = 0; fn < 4; ++fn)
                    acc[fm][fn] = __builtin_amdgcn_mfma_f32_16x16x32_bf16(a[fm], bb[fn], acc[fm][fn], 0, 0, 0);
        }
        __syncthreads();
    }
    if (mode == 2) {
        if (tid < 128) sh_mv[tid] = mvp[(size_t)b * SEQ + i0 + tid];
        __syncthreads();
    }
    const us* XCb = XC + (size_t)b * SEQ * 1024;
    float sa = 0.f, sb = 0.f, sab = 0.f;
    const int er = l & 15, eq = (l >> 4) * 4;
#pragma unroll
    for (int fm = 0; fm < 4; ++fm)
#pragma unroll
        for (int fn = 0; fn < 4; ++fn)
#pragma unroll
            for (int r = 0; r < 4; ++r) {
                const int lrow = wm + fm * 16 + eq + r;
                const int col = j0 + wn + fn * 16 + er;
                float v = acc[fm][fn][r];
                const size_t o = ((size_t)b * SEQ + i0 + lrow) * DM + col;
                const size_t xo = (size_t)(i0 + lrow) * 1024 + col;
                const float x = bf2f(XCb[xo]) + bf2f(XCb[xo + 512]);
                v += x;
                sb += v * v;
                if (mode == 2) {
                    const float a = x * sh_mv[lrow];
                    sa += a * a;
                    sab += a * v;
                }
                Cout[o] = v;
            }
#pragma unroll
    for (int off = 32; off > 0; off >>= 1) {
        sb += __shfl_xor(sb, off, 64);
        if (mode == 2) { sa += __shfl_xor(sa, off, 64); sab += __shfl_xor(sab, off, 64); }
    }
    if (l == 0) { ps[0][w] = sb; ps[1][w] = sa; ps[2][w] = sab; }
    __syncthreads();
    if (tid == 0) {
        if (mode == 1) {
            atomicAdd(&SS[SS_IDX(0, b)], ps[0][0] + ps[0][1] + ps[0][2] + ps[0][3]);
        } else {
            atomicAdd(&SS[SS_IDX(0, b)], ps[1][0] + ps[1][1] + ps[1][2] + ps[1][3]);
            atomicAdd(&SS[SS_IDX(1, b)], ps[0][0] + ps[0][1] + ps[0][2] + ps[0][3]);
            atomicAdd(&SS[SS_IDX(2, b)], ps[2][0] + ps[2][1] + ps[2][2] + ps[2][3]);
        }
    }
}

// ---------------- zero all SS stages ----------------
__global__ void k_zero(float* __restrict__ SSb) {
    const int i = blockIdx.x * 256 + threadIdx.x;
    if (i < SS_FLOATS) SSb[i] = 0.0f;
}

// ---------------- finish: v from T (+XC), write XC hi|lo + transposed bf16/f32 ----------------
// mode 0: v = f3*T ; mode 1: v = f3*(f1*x*mv + f2*T)  (T holds x+t3)
__global__ __launch_bounds__(256) void k_finish(const float* __restrict__ Tin,
                                                const us* __restrict__ XCin,
                                                const float* __restrict__ mv,
                                                const float* __restrict__ SS,
                                                us* __restrict__ XCout,
                                                us* __restrict__ XTb,
                                                float* __restrict__ XTf,
                                                int mode, int writeXC) {
    const int b = blockIdx.z;
    const int s0 = blockIdx.x * 32, d0 = blockIdx.y * 32;
    const int tx = threadIdx.x, ty = threadIdx.y;
    __shared__ float tile[32][33];
    float f1 = 0.f, f2 = 0.f, f3;
    if (mode == 0) {
        f3 = NS_F * sqrtf(DS_F / (SS[SS_IDX(0, b)] + 1e-5f));
    } else {
        const float ssa = SS[SS_IDX(0, b)], ssb = SS[SS_IDX(1, b)], ssab = SS[SS_IDX(2, b)];
        f1 = NS_F * sqrtf(DS_F / (ssa + 1e-5f));
        f2 = NS_F * sqrtf(DS_F / (ssb + 1e-5f));
        const float ssc = f1 * f1 * ssa + 2.f * f1 * f2 * ssab + f2 * f2 * ssb;
        f3 = NS_F * sqrtf(DS_F / (ssc + 1e-5f));
    }
#pragma unroll
    for (int j = 0; j < 4; ++j) {
        const int s = s0 + ty + j * 8;
        const int d = d0 + tx;
        const size_t o = ((size_t)b * SEQ + s) * DM + d;
        const size_t xo = ((size_t)b * SEQ + s) * 1024 + d;
        float v;
        if (mode == 0) v = f3 * Tin[o];
        else {
            const float x = bf2f(XCin[xo]) + bf2f(XCin[xo + 512]);
            v = f3 * (f1 * x * mv[(size_t)b * SEQ + s] + f2 * Tin[o]);
        }
        if (writeXC) {
            const us h = f2bf(v);
            XCout[xo] = h;
            XCout[xo + 512] = f2bf(v - bf2f(h));
        }
        tile[ty + j * 8][tx] = v;
    }
    __syncthreads();
#pragma unroll
    for (int j = 0; j < 4; ++j) {
        const int d = d0 + ty + j * 8;
        const int s = s0 + tx;
        const float v = tile[tx][ty + j * 8];
        const size_t o = ((size_t)b * DM + d) * SEQ + s;
        if (XTb) XTb[o] = f2bf(v);
        else if (XTf) XTf[o] = v;
    }
}

extern "C" void kernel_launch(void* const* d_in, const int* in_sizes, int n_in,
                              void* d_out, int out_size, void* d_ws, size_t ws_size,
                              hipStream_t stream) {
    const float* train_feat = (const float*)d_in[0];
    const float* test_feat  = (const float*)d_in[1];
    const float* label      = (const float*)d_in[2];
    const float* WKs        = (const float*)d_in[3];
    const float* bKs        = (const float*)d_in[4];
    const float* WKc        = (const float*)d_in[5];
    const float* bKc        = (const float*)d_in[6];
    float* out = (float*)d_out;
    float* w = (float*)d_ws;

    const size_t SBD = (size_t)NB * SEQ * DM;   // 8,388,608 elems
    const size_t SBK = (size_t)NB * SEQ * KD;

    float* T   = w;                                  // SBD f32
    us* XC     = (us*)(T + SBD);                     // 2*SBD us (hi|lo)
    us* XTd    = XC + 2 * SBD;                       // SBD us
    us* MEMT   = XTd + SBD;                          // SBD us
    us* MEMLT  = MEMT + SBD;                         // SBD us
    us* W1C    = MEMLT + SBD;                        // 2*SBK us
    us* WKMC   = W1C + 2 * SBK;                      // 2*SBK us
    us* WCs    = WKMC + 2 * SBK;                     // KD*1024 us
    us* WCc    = WCs + (size_t)KD * 1024;
    float* MVEC = (float*)(WCc + (size_t)KD * 1024); // NB*SEQ f32
    float* SS   = MVEC + (size_t)NB * SEQ;           // SS_FLOATS
    float* AFF  = SS + SS_FLOATS;                    // cap*SEQ*SEQ f32

    const size_t fixed = (size_t)(AFF - w);
    const size_t per = (size_t)SEQ * SEQ + (size_t)SEQ * SEQ / 2;  // AFF f32 + P bf16
    const size_t wsf = ws_size / 4;
    int cap = 1;
    if (wsf > fixed) {
        size_t c = (wsf - fixed) / per;
        if (c < 1) c = 1;
        if (c > NB) c = NB;
        cap = (int)c;
    }
    us* Pbuf = (us*)(AFF + (size_t)cap * SEQ * SEQ);

    const dim3 gT_in(DM / 32, SEQ / 32, NB), bT(32, 8);
    const dim3 gFin(SEQ / 32, DM / 32, NB);

    int stage = 0;
    auto nextSS = [&]() { return SS + (size_t)(stage++) * SS_STRIDE; };

    auto attn = [&](const us* Qc, const us* Kc, const us* VT,
                    const float* labelp, float* mvp, int pvmode, float* SSst) {
        for (int b0 = 0; b0 < NB; b0 += cap) {
            const int nb = (NB - b0 < cap) ? NB - b0 : cap;
            k_qk<<<dim3(8, 8, nb), 256, 0, stream>>>(Qc, Kc, AFF, b0);
            k_softmax<<<dim3(SEQ, nb), 256, 0, stream>>>(AFF, Pbuf, labelp, mvp, b0);
            k_pv<<<dim3(4, 8, nb), 256, 0, stream>>>(Pbuf, VT, XC, mvp, T, SSst, b0, pvmode);
        }
    };

    // ---------------- setup ----------------
    k_zero<<<(SS_FLOATS + 255) / 256, 256, 0, stream>>>(SS);
    k_wsplit<<<KD, 256, 0, stream>>>(WKs, WCs);
    k_wsplit<<<KD, 256, 0, stream>>>(WKc, WCc);

    // ---------------- encoder ----------------
    k_transpose_in<<<gT_in, bT, 0, stream>>>(train_feat, XC, MEMT);
    for (int l = 0; l < 2; ++l) {
        float* SSst = nextSS();
        k_proj<<<NB * SEQ / 64, 256, 0, stream>>>(XC, WCs, bKs, W1C);
        attn(W1C, W1C, MEMT, nullptr, nullptr, 1, SSst);
        k_finish<<<gFin, bT, 0, stream>>>(T, XC, nullptr, SSst, XC, MEMT, nullptr, 0, 1);
    }
    k_proj<<<NB * SEQ / 64, 256, 0, stream>>>(XC, WCc, bKc, WKMC);
    k_mklabel<<<dim3(DM * SEQ / 8 / 256, NB), 256, 0, stream>>>(MEMT, label, MEMLT);

    // ---------------- decoder (x2) ----------------
    auto decoder = [&](const float* feat, float* outp) {
        k_transpose_in<<<gT_in, bT, 0, stream>>>(feat, XC, XTd);
        for (int l = 0; l < 2; ++l) {
            // self-attn + inorm
            float* SSst = nextSS();
            k_proj<<<NB * SEQ / 64, 256, 0, stream>>>(XC, WCs, bKs, W1C);
            attn(W1C, W1C, XTd, nullptr, nullptr, 1, SSst);
            k_finish<<<gFin, bT, 0, stream>>>(T, XC, nullptr, SSst, XC, XTd, nullptr, 0, 1);
            // cross-attn (fused reduce3): T = x + t3; SS = ssa/ssb/ssab; MVEC = mask
            float* SSst2 = nextSS();
            k_proj<<<NB * SEQ / 64, 256, 0, stream>>>(XC, WCc, bKc, W1C);
            attn(W1C, WKMC, MEMLT, label, MVEC, 2, SSst2);
            // fused triple instance-norm finish
            if (l == 0)
                k_finish<<<gFin, bT, 0, stream>>>(T, XC, MVEC, SSst2, XC, XTd, nullptr, 1, 1);
            else
                k_finish<<<gFin, bT, 0, stream>>>(T, XC, MVEC, SSst2, XC, nullptr, outp, 1, 0);
        }
    };
    decoder(train_feat, out);
    decoder(test_feat, out + SBD);
}

// Round 6
// 1195.513 us; speedup vs baseline: 5.5117x; 1.1742x over previous
//
#include <hip/hip_runtime.h>
#include <math.h>

#define NB 16
#define SEQ 1024
#define DM 512
#define KD 128
#define TEMP_F 30.0f
#define NS_F 0.011048543456039805f   // sqrt(1/8192)
#define DS_F 524288.0f               // D*H*W = 512*1024

// SS: per-stage slabs; within a stage, one cache line per counter
#define SS_IDX(grp, b) (((grp) * NB + (b)) * 16)
#define SS_STRIDE 768
#define SS_STAGES 12
#define SS_FLOATS (SS_STRIDE * SS_STAGES)

typedef short bf16x8 __attribute__((ext_vector_type(8)));
typedef float f32x4 __attribute__((ext_vector_type(4)));
typedef unsigned short us;
typedef unsigned short us8 __attribute__((ext_vector_type(8)));

__device__ __forceinline__ us f2bf(float x) {
    union { float f; unsigned u; } v; v.f = x;
    unsigned r = v.u + 0x7fffu + ((v.u >> 16) & 1u);
    return (us)(r >> 16);
}
__device__ __forceinline__ float bf2f(us h) {
    union { unsigned u; float f; } v; v.u = ((unsigned)h) << 16;
    return v.f;
}

// global -> LDS async 16B/lane. lds dst = wave-uniform base + lane*16 implicit.
#define GLL16(gp, lp) __builtin_amdgcn_global_load_lds( \
    (__attribute__((address_space(1))) void*)(unsigned long long)(gp), \
    (__attribute__((address_space(3))) void*)(unsigned)(unsigned long long)(lp), 16, 0, 0)

// Swizzled LDS tile convention for [R][64] bf16 tiles staged via GLL16:
//   stage: lane l of chunk c loads global (row = base + c*8 + (l>>3),
//          colchunk = (l&7) ^ (l>>3)) into linear LDS (chunk base + l*16B).
//   read:  element (row, kk) lives at LDS elem  row*64 + (kk ^ ((row&7)<<3)).

// ---------------- transpose in: src [B][D][S] f32 -> XC [B][S][1024] bf16 hi|lo + XT [B][D][S] bf16 ----------------
__global__ __launch_bounds__(256) void k_transpose_in(const float* __restrict__ src,
                                                      us* __restrict__ XC,
                                                      us* __restrict__ XT) {
    __shared__ float tile[32][33];
    const int b = blockIdx.z;
    const int d0 = blockIdx.x * 32;
    const int s0 = blockIdx.y * 32;
    const int tx = threadIdx.x, ty = threadIdx.y;  // 32x8
    const float* p = src + (size_t)b * DM * SEQ;
    us* pt = XT + (size_t)b * DM * SEQ;
    us* pc = XC + (size_t)b * SEQ * 1024;
#pragma unroll
    for (int j = 0; j < 32; j += 8) {
        const size_t o = (size_t)(d0 + ty + j) * SEQ + s0 + tx;
        const float v = p[o];
        tile[ty + j][tx] = v;
        pt[o] = f2bf(v);
    }
    __syncthreads();
#pragma unroll
    for (int j = 0; j < 4; ++j) {
        const int s = s0 + ty + j * 8;
        const int d = d0 + tx;
        const float v = tile[tx][ty + j * 8];
        const us h = f2bf(v);
        pc[(size_t)s * 1024 + d] = h;
        pc[(size_t)s * 1024 + 512 + d] = f2bf(v - bf2f(h));
    }
}

// ---------------- MEMLT[b][d][s] = MEMT[b][d][s] * label[b][s] ----------------
__global__ __launch_bounds__(256) void k_mklabel(const us* __restrict__ MT,
                                                 const float* __restrict__ label,
                                                 us* __restrict__ ML) {
    const int b = blockIdx.y;
    const size_t off = ((size_t)blockIdx.x * 256 + threadIdx.x) * 8;
    const int s = (int)(off & (SEQ - 1));
    const size_t o = (size_t)b * DM * SEQ + off;
    us8 v = *(const us8*)(MT + o);
    const float4 l0 = *(const float4*)(label + (size_t)b * SEQ + s);
    const float4 l1 = *(const float4*)(label + (size_t)b * SEQ + s + 4);
    us8 r;
    r[0] = f2bf(bf2f(v[0]) * l0.x); r[1] = f2bf(bf2f(v[1]) * l0.y);
    r[2] = f2bf(bf2f(v[2]) * l0.z); r[3] = f2bf(bf2f(v[3]) * l0.w);
    r[4] = f2bf(bf2f(v[4]) * l1.x); r[5] = f2bf(bf2f(v[5]) * l1.y);
    r[6] = f2bf(bf2f(v[6]) * l1.z); r[7] = f2bf(bf2f(v[7]) * l1.w);
    *(us8*)(ML + o) = r;
}

// ---------------- weight split: WK [DM][KD] f32 -> WC [KD][1024] bf16 hi|lo ----------------
__global__ __launch_bounds__(256) void k_wsplit(const float* __restrict__ WK,
                                                us* __restrict__ WC) {
    const int k = blockIdx.x;  // 0..KD
    for (int d = threadIdx.x; d < DM; d += 256) {
        const float v = WK[(size_t)d * KD + k];
        const us h = f2bf(v);
        WC[(size_t)k * 1024 + d] = h;
        WC[(size_t)k * 1024 + 512 + d] = f2bf(v - bf2f(h));
    }
}

// ---------------- projection GEMM: W1C[row][0:128]=hi,[128:256]=lo of l2norm(X@WK+bK) ----------------
// Tile 64 rows x 128 cols, 4 waves (2m x 2n), virtual K=1536: A=[xh|xl|xh], B=[wh|wh|wl].
__global__ __launch_bounds__(256) void k_proj(const us* __restrict__ XC,
                                              const us* __restrict__ WC,
                                              const float* __restrict__ bK,
                                              us* __restrict__ Wout) {
    const int row0 = blockIdx.x * 64;
    __shared__ short As[64 * 64], Bs[128 * 64];
    __shared__ float ssp[2][64];
    const int tid = threadIdx.x, w = tid >> 6, l = tid & 63;
    const int wm = (w >> 1) * 32, wn = (w & 1) * 64;
    const int sr = l >> 3, sc = (((l & 7) ^ (l >> 3)) << 3);
    const int lr = l & 15, lk = (l >> 4) * 8;
    const int sx = (lr & 7) << 3;
    f32x4 acc[2][4] = {};
    for (int k0 = 0; k0 < 1536; k0 += 64) {
        const int ak0 = (k0 < 1024) ? k0 : k0 - 1024;
        const int bk0 = (k0 < 512) ? k0 : k0 - 512;
#pragma unroll
        for (int cc = 0; cc < 2; ++cc) {
            const int c = 2 * w + cc;
            GLL16(XC + (size_t)(row0 + c * 8 + sr) * 1024 + ak0 + sc, &As[c * 512]);
        }
#pragma unroll
        for (int cc = 0; cc < 4; ++cc) {
            const int c = 4 * w + cc;
            GLL16(WC + (size_t)(c * 8 + sr) * 1024 + bk0 + sc, &Bs[c * 512]);
        }
        __syncthreads();
#pragma unroll
        for (int kc = 0; kc < 2; ++kc) {
            const int kk = kc * 32 + lk;
            bf16x8 a[2], bb[4];
#pragma unroll
            for (int fm = 0; fm < 2; ++fm)
                a[fm] = *(const bf16x8*)&As[(wm + fm * 16 + lr) * 64 + (kk ^ sx)];
#pragma unroll
            for (int fn = 0; fn < 4; ++fn)
                bb[fn] = *(const bf16x8*)&Bs[(wn + fn * 16 + lr) * 64 + (kk ^ sx)];
#pragma unroll
            for (int fm = 0; fm < 2; ++fm)
#pragma unroll
                for (int fn = 0; fn < 4; ++fn)
                    acc[fm][fn] = __builtin_amdgcn_mfma_f32_16x16x32_bf16(a[fm], bb[fn], acc[fm][fn], 0, 0, 0);
        }
        __syncthreads();
    }
    const int er = l & 15, eq = (l >> 4) * 4;
    const int nh = w & 1;
    float bkv[4];
#pragma unroll
    for (int fn = 0; fn < 4; ++fn) bkv[fn] = bK[wn + fn * 16 + er];
    float vv[2][4][4];
#pragma unroll
    for (int fm = 0; fm < 2; ++fm)
#pragma unroll
        for (int r = 0; r < 4; ++r) {
            float ss = 0.f;
#pragma unroll
            for (int fn = 0; fn < 4; ++fn) {
                const float t = acc[fm][fn][r] + bkv[fn];
                vv[fm][fn][r] = t;
                ss += t * t;
            }
#pragma unroll
            for (int o = 8; o > 0; o >>= 1) ss += __shfl_xor(ss, o, 64);
            if (er == 0) ssp[nh][wm + fm * 16 + eq + r] = ss;
        }
    __syncthreads();
#pragma unroll
    for (int fm = 0; fm < 2; ++fm)
#pragma unroll
        for (int r = 0; r < 4; ++r) {
            const int rowloc = wm + fm * 16 + eq + r;
            const float tot = ssp[0][rowloc] + ssp[1][rowloc];
            const float invn = 1.0f / fmaxf(sqrtf(tot), 1e-12f);
            const size_t ro = (size_t)(row0 + rowloc) * 256;
#pragma unroll
            for (int fn = 0; fn < 4; ++fn) {
                const float ov = vv[fm][fn][r] * invn;
                const us h = f2bf(ov);
                Wout[ro + wn + fn * 16 + er] = h;
                Wout[ro + 128 + wn + fn * 16 + er] = f2bf(ov - bf2f(h));
            }
        }
}

// ---------------- QK^T GEMM + fixed-max exp: P~ = exp(TEMP*(dot-1)) bf16; row partials RS/RL ----------------
// virtual K=384 ([qh|ql|qh] x [kh|kh|kl]); softmax is shift-invariant, logits <= TEMP.
__global__ __launch_bounds__(256) void k_qk(const us* __restrict__ Qc,
                                            const us* __restrict__ Kc,
                                            const float* __restrict__ labelp,
                                            us* __restrict__ P,
                                            float* __restrict__ RS,
                                            float* __restrict__ RL, int b0) {
    const int bz = blockIdx.z, b = b0 + bz;
    const int i0 = blockIdx.y * 128, j0 = blockIdx.x * 128;
    const int jb = blockIdx.x;
    const us* Ab = Qc + (size_t)b * SEQ * 256;
    const us* Bb = Kc + (size_t)b * SEQ * 256;
    __shared__ short As[128 * 64], Bs[128 * 64];
    __shared__ float shrs[2][128], shrl[2][128];
    const int tid = threadIdx.x, w = tid >> 6, l = tid & 63;
    const int wm = (w >> 1) * 64, wn = (w & 1) * 64;
    const int sr = l >> 3, sc = (((l & 7) ^ (l >> 3)) << 3);
    const int lr = l & 15, lk = (l >> 4) * 8;
    const int sx = (lr & 7) << 3;
    f32x4 acc[4][4] = {};
    for (int k0 = 0; k0 < 384; k0 += 64) {
        const int ak0 = (k0 < 256) ? k0 : k0 - 256;
        const int bk0 = (k0 < 128) ? k0 : k0 - 128;
#pragma unroll
        for (int cc = 0; cc < 4; ++cc) {
            const int c = 4 * w + cc;
            GLL16(Ab + (size_t)(i0 + c * 8 + sr) * 256 + ak0 + sc, &As[c * 512]);
            GLL16(Bb + (size_t)(j0 + c * 8 + sr) * 256 + bk0 + sc, &Bs[c * 512]);
        }
        __syncthreads();
#pragma unroll
        for (int kc = 0; kc < 2; ++kc) {
            const int kk = kc * 32 + lk;
            bf16x8 a[4], bb[4];
#pragma unroll
            for (int f = 0; f < 4; ++f) {
                a[f]  = *(const bf16x8*)&As[(wm + f * 16 + lr) * 64 + (kk ^ sx)];
                bb[f] = *(const bf16x8*)&Bs[(wn + f * 16 + lr) * 64 + (kk ^ sx)];
            }
#pragma unroll
            for (int fm = 0; fm < 4; ++fm)
#pragma unroll
                for (int fn = 0; fn < 4; ++fn)
                    acc[fm][fn] = __builtin_amdgcn_mfma_f32_16x16x32_bf16(a[fm], bb[fn], acc[fm][fn], 0, 0, 0);
        }
        __syncthreads();
    }
    us* Pb = P + (size_t)bz * SEQ * SEQ;
    const int er = l & 15, eq = (l >> 4) * 4;
    float lb[4] = {0.f, 0.f, 0.f, 0.f};
    if (labelp) {
#pragma unroll
        for (int fn = 0; fn < 4; ++fn) lb[fn] = labelp[(size_t)b * SEQ + j0 + wn + fn * 16 + er];
    }
#pragma unroll
    for (int fm = 0; fm < 4; ++fm)
#pragma unroll
        for (int r = 0; r < 4; ++r) {
            float s = 0.f, sl = 0.f;
#pragma unroll
            for (int fn = 0; fn < 4; ++fn) {
                const float e = __expf(fmaf(TEMP_F, acc[fm][fn][r], -TEMP_F));
                Pb[(size_t)(i0 + wm + fm * 16 + eq + r) * SEQ + j0 + wn + fn * 16 + er] = f2bf(e);
                s += e;
                sl += e * lb[fn];
            }
#pragma unroll
            for (int o = 1; o < 16; o <<= 1) {
                s += __shfl_xor(s, o, 64);
                sl += __shfl_xor(sl, o, 64);
            }
            if (er == 0) {
                shrs[w & 1][wm + fm * 16 + eq + r] = s;
                shrl[w & 1][wm + fm * 16 + eq + r] = sl;
            }
        }
    __syncthreads();
    if (tid < 128) {
        const size_t o = ((size_t)b * 8 + jb) * SEQ + i0 + tid;
        RS[o] = shrs[0][tid] + shrs[1][tid];
        if (labelp) RL[o] = shrl[0][tid] + shrl[1][tid];
    }
}

// ---------------- PV GEMM: acc = P~ x VT^T (K=SEQ); epilogue: normalize by rowsum, residual, SS ----------------
// mode 1: T = acc/rs + x, ssq -> SS[0][b]            (self)
// mode 2: T = acc/rs + x; mvec=(RLsum)/rs; sa=(x*m)^2 sb sab  (cross)
__global__ __launch_bounds__(256) void k_pv(const us* __restrict__ P,
                                            const us* __restrict__ VT,
                                            const us* __restrict__ XC,
                                            const float* __restrict__ RS,
                                            const float* __restrict__ RL,
                                            float* __restrict__ MVEC,
                                            float* __restrict__ Cout,
                                            float* __restrict__ SS, int b0, int mode) {
    const int bz = blockIdx.z, b = b0 + bz;
    const int i0 = blockIdx.y * 128, j0 = blockIdx.x * 128;
    const us* Pb = P + (size_t)bz * SEQ * SEQ;
    const us* Vb = VT + (size_t)b * DM * SEQ;
    __shared__ short As[128 * 64], Bs[128 * 64];
    __shared__ float sh_inv[128], sh_m[128];
    __shared__ float ps[3][4];
    const int tid = threadIdx.x, w = tid >> 6, l = tid & 63;
    const int wm = (w >> 1) * 64, wn = (w & 1) * 64;
    const int sr = l >> 3, sc = (((l & 7) ^ (l >> 3)) << 3);
    const int lr = l & 15, lk = (l >> 4) * 8;
    const int sx = (lr & 7) << 3;
    f32x4 acc[4][4] = {};
    for (int k0 = 0; k0 < SEQ; k0 += 64) {
#pragma unroll
        for (int cc = 0; cc < 4; ++cc) {
            const int c = 4 * w + cc;
            GLL16(Pb + (size_t)(i0 + c * 8 + sr) * SEQ + k0 + sc, &As[c * 512]);
            GLL16(Vb + (size_t)(j0 + c * 8 + sr) * SEQ + k0 + sc, &Bs[c * 512]);
        }
        __syncthreads();
#pragma unroll
        for (int kc = 0; kc < 2; ++kc) {
            const int kk = kc * 32 + lk;
            bf16x8 a[4], bb[4];
#pragma unroll
            for (int f = 0; f < 4; ++f) {
                a[f]  = *(const bf16x8*)&As[(wm + f * 16 + lr) * 64 + (kk ^ sx)];
                bb[f] = *(const bf16x8*)&Bs[(wn + f * 16 + lr) * 64 + (kk ^ sx)];
            }
#pragma unroll
            for (int fm = 0; fm < 4; ++fm)
#pragma unroll
                for (int fn = 0; fn < 4; ++fn)
                    acc[fm][fn] = __builtin_amdgcn_mfma_f32_16x16x32_bf16(a[fm], bb[fn], acc[fm][fn], 0, 0, 0);
        }
        __syncthreads();
    }
    // rowsum normalization factors (+ mvec for cross)
    if (tid < 128) {
        const size_t base = (size_t)b * 8 * SEQ + i0 + tid;
        float s = 0.f;
#pragma unroll
        for (int jb = 0; jb < 8; ++jb) s += RS[base + (size_t)jb * SEQ];
        const float inv = 1.0f / s;
        sh_inv[tid] = inv;
        if (mode == 2) {
            float sl = 0.f;
#pragma unroll
            for (int jb = 0; jb < 8; ++jb) sl += RL[base + (size_t)jb * SEQ];
            const float mv = sl * inv;
            sh_m[tid] = mv;
            if (blockIdx.x == 0) MVEC[(size_t)b * SEQ + i0 + tid] = mv;
        }
    }
    __syncthreads();
    const us* XCb = XC + (size_t)b * SEQ * 1024;
    float sa = 0.f, sb = 0.f, sab = 0.f;
    const int er = l & 15, eq = (l >> 4) * 4;
#pragma unroll
    for (int fm = 0; fm < 4; ++fm)
#pragma unroll
        for (int fn = 0; fn < 4; ++fn)
#pragma unroll
            for (int r = 0; r < 4; ++r) {
                const int lrow = wm + fm * 16 + eq + r;
                const int col = j0 + wn + fn * 16 + er;
                float v = acc[fm][fn][r] * sh_inv[lrow];
                const size_t o = ((size_t)b * SEQ + i0 + lrow) * DM + col;
                const size_t xo = (size_t)(i0 + lrow) * 1024 + col;
                const float x = bf2f(XCb[xo]) + bf2f(XCb[xo + 512]);
                v += x;
                sb += v * v;
                if (mode == 2) {
                    const float a = x * sh_m[lrow];
                    sa += a * a;
                    sab += a * v;
                }
                Cout[o] = v;
            }
#pragma unroll
    for (int off = 32; off > 0; off >>= 1) {
        sb += __shfl_xor(sb, off, 64);
        if (mode == 2) { sa += __shfl_xor(sa, off, 64); sab += __shfl_xor(sab, off, 64); }
    }
    if (l == 0) { ps[0][w] = sb; ps[1][w] = sa; ps[2][w] = sab; }
    __syncthreads();
    if (tid == 0) {
        if (mode == 1) {
            atomicAdd(&SS[SS_IDX(0, b)], ps[0][0] + ps[0][1] + ps[0][2] + ps[0][3]);
        } else {
            atomicAdd(&SS[SS_IDX(0, b)], ps[1][0] + ps[1][1] + ps[1][2] + ps[1][3]);
            atomicAdd(&SS[SS_IDX(1, b)], ps[0][0] + ps[0][1] + ps[0][2] + ps[0][3]);
            atomicAdd(&SS[SS_IDX(2, b)], ps[2][0] + ps[2][1] + ps[2][2] + ps[2][3]);
        }
    }
}

// ---------------- zero all SS stages ----------------
__global__ void k_zero(float* __restrict__ SSb) {
    const int i = blockIdx.x * 256 + threadIdx.x;
    if (i < SS_FLOATS) SSb[i] = 0.0f;
}

// ---------------- finish: v from T (+XC), write XC hi|lo + transposed bf16/f32 ----------------
// mode 0: v = f3*T ; mode 1: v = f3*(f1*x*mv + f2*T)  (T holds x+t3)
__global__ __launch_bounds__(256) void k_finish(const float* __restrict__ Tin,
                                                const us* __restrict__ XCin,
                                                const float* __restrict__ mv,
                                                const float* __restrict__ SS,
                                                us* __restrict__ XCout,
                                                us* __restrict__ XTb,
                                                float* __restrict__ XTf,
                                                int mode, int writeXC) {
    const int b = blockIdx.z;
    const int s0 = blockIdx.x * 32, d0 = blockIdx.y * 32;
    const int tx = threadIdx.x, ty = threadIdx.y;
    __shared__ float tile[32][33];
    float f1 = 0.f, f2 = 0.f, f3;
    if (mode == 0) {
        f3 = NS_F * sqrtf(DS_F / (SS[SS_IDX(0, b)] + 1e-5f));
    } else {
        const float ssa = SS[SS_IDX(0, b)], ssb = SS[SS_IDX(1, b)], ssab = SS[SS_IDX(2, b)];
        f1 = NS_F * sqrtf(DS_F / (ssa + 1e-5f));
        f2 = NS_F * sqrtf(DS_F / (ssb + 1e-5f));
        const float ssc = f1 * f1 * ssa + 2.f * f1 * f2 * ssab + f2 * f2 * ssb;
        f3 = NS_F * sqrtf(DS_F / (ssc + 1e-5f));
    }
#pragma unroll
    for (int j = 0; j < 4; ++j) {
        const int s = s0 + ty + j * 8;
        const int d = d0 + tx;
        const size_t o = ((size_t)b * SEQ + s) * DM + d;
        const size_t xo = ((size_t)b * SEQ + s) * 1024 + d;
        float v;
        if (mode == 0) v = f3 * Tin[o];
        else {
            const float x = bf2f(XCin[xo]) + bf2f(XCin[xo + 512]);
            v = f3 * (f1 * x * mv[(size_t)b * SEQ + s] + f2 * Tin[o]);
        }
        if (writeXC) {
            const us h = f2bf(v);
            XCout[xo] = h;
            XCout[xo + 512] = f2bf(v - bf2f(h));
        }
        tile[ty + j * 8][tx] = v;
    }
    __syncthreads();
#pragma unroll
    for (int j = 0; j < 4; ++j) {
        const int d = d0 + ty + j * 8;
        const int s = s0 + tx;
        const float v = tile[tx][ty + j * 8];
        const size_t o = ((size_t)b * DM + d) * SEQ + s;
        if (XTb) XTb[o] = f2bf(v);
        else if (XTf) XTf[o] = v;
    }
}

extern "C" void kernel_launch(void* const* d_in, const int* in_sizes, int n_in,
                              void* d_out, int out_size, void* d_ws, size_t ws_size,
                              hipStream_t stream) {
    const float* train_feat = (const float*)d_in[0];
    const float* test_feat  = (const float*)d_in[1];
    const float* label      = (const float*)d_in[2];
    const float* WKs        = (const float*)d_in[3];
    const float* bKs        = (const float*)d_in[4];
    const float* WKc        = (const float*)d_in[5];
    const float* bKc        = (const float*)d_in[6];
    float* out = (float*)d_out;
    float* w = (float*)d_ws;

    const size_t SBD = (size_t)NB * SEQ * DM;   // 8,388,608 elems
    const size_t SBK = (size_t)NB * SEQ * KD;

    float* T   = w;                                  // SBD f32
    us* XC     = (us*)(T + SBD);                     // 2*SBD us (hi|lo)
    us* XTd    = XC + 2 * SBD;                       // SBD us
    us* MEMT   = XTd + SBD;                          // SBD us
    us* MEMLT  = MEMT + SBD;                         // SBD us
    us* W1C    = MEMLT + SBD;                        // 2*SBK us
    us* WKMC   = W1C + 2 * SBK;                      // 2*SBK us
    us* WCs    = WKMC + 2 * SBK;                     // KD*1024 us
    us* WCc    = WCs + (size_t)KD * 1024;
    float* MVEC = (float*)(WCc + (size_t)KD * 1024); // NB*SEQ f32
    float* SS   = MVEC + (size_t)NB * SEQ;           // SS_FLOATS
    float* RS   = SS + SS_FLOATS;                    // NB*8*SEQ f32
    float* RL   = RS + (size_t)NB * 8 * SEQ;         // NB*8*SEQ f32
    float* Pf   = RL + (size_t)NB * 8 * SEQ;         // cap*SEQ*SEQ/2 f32-equiv (P bf16)

    const size_t fixed = (size_t)(Pf - w);
    const size_t per = (size_t)SEQ * SEQ / 2;  // P bf16 per batch, in f32 units
    const size_t wsf = ws_size / 4;
    int cap = 1;
    if (wsf > fixed) {
        size_t c = (wsf - fixed) / per;
        if (c < 1) c = 1;
        if (c > NB) c = NB;
        cap = (int)c;
    }
    us* Pbuf = (us*)Pf;

    const dim3 gT_in(DM / 32, SEQ / 32, NB), bT(32, 8);
    const dim3 gFin(SEQ / 32, DM / 32, NB);

    int stage = 0;
    auto nextSS = [&]() { return SS + (size_t)(stage++) * SS_STRIDE; };

    auto attn = [&](const us* Qc, const us* Kc, const us* VT,
                    const float* labelp, int pvmode, float* SSst) {
        for (int b0 = 0; b0 < NB; b0 += cap) {
            const int nb = (NB - b0 < cap) ? NB - b0 : cap;
            k_qk<<<dim3(8, 8, nb), 256, 0, stream>>>(Qc, Kc, labelp, Pbuf, RS, RL, b0);
            k_pv<<<dim3(4, 8, nb), 256, 0, stream>>>(Pbuf, VT, XC, RS, RL, MVEC, T, SSst, b0, pvmode);
        }
    };

    // ---------------- setup ----------------
    k_zero<<<(SS_FLOATS + 255) / 256, 256, 0, stream>>>(SS);
    k_wsplit<<<KD, 256, 0, stream>>>(WKs, WCs);
    k_wsplit<<<KD, 256, 0, stream>>>(WKc, WCc);

    // ---------------- encoder ----------------
    k_transpose_in<<<gT_in, bT, 0, stream>>>(train_feat, XC, MEMT);
    for (int l = 0; l < 2; ++l) {
        float* SSst = nextSS();
        k_proj<<<NB * SEQ / 64, 256, 0, stream>>>(XC, WCs, bKs, W1C);
        attn(W1C, W1C, MEMT, nullptr, 1, SSst);
        k_finish<<<gFin, bT, 0, stream>>>(T, XC, nullptr, SSst, XC, MEMT, nullptr, 0, 1);
    }
    k_proj<<<NB * SEQ / 64, 256, 0, stream>>>(XC, WCc, bKc, WKMC);
    k_mklabel<<<dim3(DM * SEQ / 8 / 256, NB), 256, 0, stream>>>(MEMT, label, MEMLT);

    // ---------------- decoder (x2) ----------------
    auto decoder = [&](const float* feat, float* outp) {
        k_transpose_in<<<gT_in, bT, 0, stream>>>(feat, XC, XTd);
        for (int l = 0; l < 2; ++l) {
            // self-attn + inorm
            float* SSst = nextSS();
            k_proj<<<NB * SEQ / 64, 256, 0, stream>>>(XC, WCs, bKs, W1C);
            attn(W1C, W1C, XTd, nullptr, 1, SSst);
            k_finish<<<gFin, bT, 0, stream>>>(T, XC, nullptr, SSst, XC, XTd, nullptr, 0, 1);
            // cross-attn (fused reduce3): T = x + t3; SS = ssa/ssb/ssab; MVEC = mask
            float* SSst2 = nextSS();
            k_proj<<<NB * SEQ / 64, 256, 0, stream>>>(XC, WCc, bKc, W1C);
            attn(W1C, WKMC, MEMLT, label, 2, SSst2);
            // fused triple instance-norm finish
            if (l == 0)
                k_finish<<<gFin, bT, 0, stream>>>(T, XC, MVEC, SSst2, XC, XTd, nullptr, 1, 1);
            else
                k_finish<<<gFin, bT, 0, stream>>>(T, XC, MVEC, SSst2, XC, nullptr, outp, 1, 0);
        }
    };
    decoder(train_feat, out);
    decoder(test_feat, out + SBD);
}

// Round 7
// 1012.682 us; speedup vs baseline: 6.5067x; 1.1805x over previous
//
#include <hip/hip_runtime.h>
#include <math.h>

#define NB 16
#define SEQ 1024
#define DM 512
#define KD 128
#define TEMP_F 30.0f
#define NS_F 0.011048543456039805f   // sqrt(1/8192)
#define DS_F 524288.0f               // D*H*W = 512*1024

// SS: per-stage slabs; within a stage, one cache line per counter
#define SS_IDX(grp, b) (((grp) * NB + (b)) * 16)
#define SS_STRIDE 768
#define SS_STAGES 12
#define SS_FLOATS (SS_STRIDE * SS_STAGES)

typedef short bf16x8 __attribute__((ext_vector_type(8)));
typedef float f32x4 __attribute__((ext_vector_type(4)));
typedef unsigned short us;
typedef unsigned short us8 __attribute__((ext_vector_type(8)));

__device__ __forceinline__ us f2bf(float x) {
    union { float f; unsigned u; } v; v.f = x;
    unsigned r = v.u + 0x7fffu + ((v.u >> 16) & 1u);
    return (us)(r >> 16);
}
__device__ __forceinline__ float bf2f(us h) {
    union { unsigned u; float f; } v; v.u = ((unsigned)h) << 16;
    return v.f;
}

// global -> LDS async 16B/lane. lds dst = wave-uniform base + lane*16 implicit.
#define GLL16(gp, lp) __builtin_amdgcn_global_load_lds( \
    (__attribute__((address_space(1))) void*)(unsigned long long)(gp), \
    (__attribute__((address_space(3))) void*)(unsigned)(unsigned long long)(lp), 16, 0, 0)

// Swizzled LDS tile convention for [R][64] bf16 tiles staged via GLL16:
//   stage: lane l of chunk c loads global (row = base + c*8 + (l>>3),
//          colchunk = (l&7) ^ (l>>3)) into linear LDS (chunk base + l*16B).
//   read:  element (row, kk) lives at LDS elem  row*64 + (kk ^ ((row&7)<<3)).

// ---------------- transpose in: src [B][D][S] f32 -> XC [B][S][1024] bf16 hi|lo + XT [B][D][S] bf16 ----------------
__global__ __launch_bounds__(256) void k_transpose_in(const float* __restrict__ src,
                                                      us* __restrict__ XC,
                                                      us* __restrict__ XT) {
    __shared__ float tile[32][33];
    const int b = blockIdx.z;
    const int d0 = blockIdx.x * 32;
    const int s0 = blockIdx.y * 32;
    const int tx = threadIdx.x, ty = threadIdx.y;  // 32x8
    const float* p = src + (size_t)b * DM * SEQ;
    us* pt = XT + (size_t)b * DM * SEQ;
    us* pc = XC + (size_t)b * SEQ * 1024;
#pragma unroll
    for (int j = 0; j < 32; j += 8) {
        const size_t o = (size_t)(d0 + ty + j) * SEQ + s0 + tx;
        const float v = p[o];
        tile[ty + j][tx] = v;
        pt[o] = f2bf(v);
    }
    __syncthreads();
#pragma unroll
    for (int j = 0; j < 4; ++j) {
        const int s = s0 + ty + j * 8;
        const int d = d0 + tx;
        const float v = tile[tx][ty + j * 8];
        const us h = f2bf(v);
        pc[(size_t)s * 1024 + d] = h;
        pc[(size_t)s * 1024 + 512 + d] = f2bf(v - bf2f(h));
    }
}

// ---------------- MEMLT[b][d][s] = MEMT[b][d][s] * label[b][s] ----------------
__global__ __launch_bounds__(256) void k_mklabel(const us* __restrict__ MT,
                                                 const float* __restrict__ label,
                                                 us* __restrict__ ML) {
    const int b = blockIdx.y;
    const size_t off = ((size_t)blockIdx.x * 256 + threadIdx.x) * 8;
    const int s = (int)(off & (SEQ - 1));
    const size_t o = (size_t)b * DM * SEQ + off;
    us8 v = *(const us8*)(MT + o);
    const float4 l0 = *(const float4*)(label + (size_t)b * SEQ + s);
    const float4 l1 = *(const float4*)(label + (size_t)b * SEQ + s + 4);
    us8 r;
    r[0] = f2bf(bf2f(v[0]) * l0.x); r[1] = f2bf(bf2f(v[1]) * l0.y);
    r[2] = f2bf(bf2f(v[2]) * l0.z); r[3] = f2bf(bf2f(v[3]) * l0.w);
    r[4] = f2bf(bf2f(v[4]) * l1.x); r[5] = f2bf(bf2f(v[5]) * l1.y);
    r[6] = f2bf(bf2f(v[6]) * l1.z); r[7] = f2bf(bf2f(v[7]) * l1.w);
    *(us8*)(ML + o) = r;
}

// ---------------- weight split: WK [DM][KD] f32 -> WC [KD][1024] bf16 hi|lo ----------------
__global__ __launch_bounds__(256) void k_wsplit(const float* __restrict__ WK,
                                                us* __restrict__ WC) {
    const int k = blockIdx.x;  // 0..KD
    for (int d = threadIdx.x; d < DM; d += 256) {
        const float v = WK[(size_t)d * KD + k];
        const us h = f2bf(v);
        WC[(size_t)k * 1024 + d] = h;
        WC[(size_t)k * 1024 + 512 + d] = f2bf(v - bf2f(h));
    }
}

// ---------------- projection GEMM: Wout[row][0:128]=hi,[128:256]=lo of l2norm(X@WK+bK) ----------------
// Tile 32 rows x 128 cols, 4 waves (2m x 2n, wave=16x64), virtual K=1536: A=[xh|xl|xh], B=[wh|wh|wl].
__global__ __launch_bounds__(256) void k_proj(const us* __restrict__ XC,
                                              const us* __restrict__ WC,
                                              const float* __restrict__ bK,
                                              us* __restrict__ Wout) {
    const int row0 = blockIdx.x * 32;
    __shared__ short As[32 * 64], Bs[128 * 64];
    __shared__ float ssp[2][32];
    const int tid = threadIdx.x, w = tid >> 6, l = tid & 63;
    const int wm = (w >> 1) * 16, wn = (w & 1) * 64;
    const int sr = l >> 3, sc = (((l & 7) ^ (l >> 3)) << 3);
    const int lr = l & 15, lk = (l >> 4) * 8;
    const int sx = (lr & 7) << 3;
    f32x4 acc[4] = {};
    for (int k0 = 0; k0 < 1536; k0 += 64) {
        const int ak0 = (k0 < 1024) ? k0 : k0 - 1024;
        const int bk0 = (k0 < 512) ? k0 : k0 - 512;
        GLL16(XC + (size_t)(row0 + w * 8 + sr) * 1024 + ak0 + sc, &As[w * 512]);
#pragma unroll
        for (int cc = 0; cc < 4; ++cc) {
            const int c = 4 * w + cc;
            GLL16(WC + (size_t)(c * 8 + sr) * 1024 + bk0 + sc, &Bs[c * 512]);
        }
        __syncthreads();
#pragma unroll
        for (int kc = 0; kc < 2; ++kc) {
            const int kk = kc * 32 + lk;
            const bf16x8 a = *(const bf16x8*)&As[(wm + lr) * 64 + (kk ^ sx)];
            bf16x8 bb[4];
#pragma unroll
            for (int fn = 0; fn < 4; ++fn)
                bb[fn] = *(const bf16x8*)&Bs[(wn + fn * 16 + lr) * 64 + (kk ^ sx)];
#pragma unroll
            for (int fn = 0; fn < 4; ++fn)
                acc[fn] = __builtin_amdgcn_mfma_f32_16x16x32_bf16(a, bb[fn], acc[fn], 0, 0, 0);
        }
        __syncthreads();
    }
    const int er = l & 15, eq = (l >> 4) * 4;
    const int nh = w & 1;
    float bkv[4];
#pragma unroll
    for (int fn = 0; fn < 4; ++fn) bkv[fn] = bK[wn + fn * 16 + er];
    float vv[4][4];
#pragma unroll
    for (int r = 0; r < 4; ++r) {
        float ss = 0.f;
#pragma unroll
        for (int fn = 0; fn < 4; ++fn) {
            const float t = acc[fn][r] + bkv[fn];
            vv[fn][r] = t;
            ss += t * t;
        }
#pragma unroll
        for (int o = 8; o > 0; o >>= 1) ss += __shfl_xor(ss, o, 64);
        if (er == 0) ssp[nh][wm + eq + r] = ss;
    }
    __syncthreads();
#pragma unroll
    for (int r = 0; r < 4; ++r) {
        const int rowloc = wm + eq + r;
        const float tot = ssp[0][rowloc] + ssp[1][rowloc];
        const float invn = 1.0f / fmaxf(sqrtf(tot), 1e-12f);
        const size_t ro = (size_t)(row0 + rowloc) * 256;
#pragma unroll
        for (int fn = 0; fn < 4; ++fn) {
            const float ov = vv[fn][r] * invn;
            const us h = f2bf(ov);
            Wout[ro + wn + fn * 16 + er] = h;
            Wout[ro + 128 + wn + fn * 16 + er] = f2bf(ov - bf2f(h));
        }
    }
}

// ---------------- QK^T GEMM + fixed-max exp: P~ = exp(TEMP*(dot-1)) bf16; row partials RS/RL ----------------
// virtual K=384 ([qh|ql|qh] x [kh|kh|kl]); XCD chunk-swizzled grid (8,8,nb).
__global__ __launch_bounds__(256) void k_qk(const us* __restrict__ Qc,
                                            const us* __restrict__ Kc,
                                            const float* __restrict__ labelp,
                                            us* __restrict__ P,
                                            float* __restrict__ RS,
                                            float* __restrict__ RL, int b0) {
    const int flat = blockIdx.x + (int)gridDim.x * (blockIdx.y + (int)gridDim.y * blockIdx.z);
    const int chunk = ((int)gridDim.x * (int)gridDim.y * (int)gridDim.z) >> 3;
    const int logical = (flat & 7) * chunk + (flat >> 3);
    const int jx = logical & 7;
    const int iy = (logical >> 3) & 7;
    const int bz = logical >> 6;
    const int b = b0 + bz;
    const int i0 = iy * 128, j0 = jx * 128;
    const int jb = jx;
    const us* Ab = Qc + (size_t)b * SEQ * 256;
    const us* Bb = Kc + (size_t)b * SEQ * 256;
    __shared__ short As[128 * 64], Bs[128 * 64];
    __shared__ float shrs[2][128], shrl[2][128];
    const int tid = threadIdx.x, w = tid >> 6, l = tid & 63;
    const int wm = (w >> 1) * 64, wn = (w & 1) * 64;
    const int sr = l >> 3, sc = (((l & 7) ^ (l >> 3)) << 3);
    const int lr = l & 15, lk = (l >> 4) * 8;
    const int sx = (lr & 7) << 3;
    f32x4 acc[4][4] = {};
    for (int k0 = 0; k0 < 384; k0 += 64) {
        const int ak0 = (k0 < 256) ? k0 : k0 - 256;
        const int bk0 = (k0 < 128) ? k0 : k0 - 128;
#pragma unroll
        for (int cc = 0; cc < 4; ++cc) {
            const int c = 4 * w + cc;
            GLL16(Ab + (size_t)(i0 + c * 8 + sr) * 256 + ak0 + sc, &As[c * 512]);
            GLL16(Bb + (size_t)(j0 + c * 8 + sr) * 256 + bk0 + sc, &Bs[c * 512]);
        }
        __syncthreads();
#pragma unroll
        for (int kc = 0; kc < 2; ++kc) {
            const int kk = kc * 32 + lk;
            bf16x8 a[4], bb[4];
#pragma unroll
            for (int f = 0; f < 4; ++f) {
                a[f]  = *(const bf16x8*)&As[(wm + f * 16 + lr) * 64 + (kk ^ sx)];
                bb[f] = *(const bf16x8*)&Bs[(wn + f * 16 + lr) * 64 + (kk ^ sx)];
            }
#pragma unroll
            for (int fm = 0; fm < 4; ++fm)
#pragma unroll
                for (int fn = 0; fn < 4; ++fn)
                    acc[fm][fn] = __builtin_amdgcn_mfma_f32_16x16x32_bf16(a[fm], bb[fn], acc[fm][fn], 0, 0, 0);
        }
        __syncthreads();
    }
    us* Pb = P + (size_t)bz * SEQ * SEQ;
    const int er = l & 15, eq = (l >> 4) * 4;
    float lb[4] = {0.f, 0.f, 0.f, 0.f};
    if (labelp) {
#pragma unroll
        for (int fn = 0; fn < 4; ++fn) lb[fn] = labelp[(size_t)b * SEQ + j0 + wn + fn * 16 + er];
    }
#pragma unroll
    for (int fm = 0; fm < 4; ++fm)
#pragma unroll
        for (int r = 0; r < 4; ++r) {
            float s = 0.f, sl = 0.f;
#pragma unroll
            for (int fn = 0; fn < 4; ++fn) {
                const float e = __expf(fmaf(TEMP_F, acc[fm][fn][r], -TEMP_F));
                Pb[(size_t)(i0 + wm + fm * 16 + eq + r) * SEQ + j0 + wn + fn * 16 + er] = f2bf(e);
                s += e;
                sl += e * lb[fn];
            }
#pragma unroll
            for (int o = 1; o < 16; o <<= 1) {
                s += __shfl_xor(s, o, 64);
                sl += __shfl_xor(sl, o, 64);
            }
            if (er == 0) {
                shrs[w & 1][wm + fm * 16 + eq + r] = s;
                shrl[w & 1][wm + fm * 16 + eq + r] = sl;
            }
        }
    __syncthreads();
    if (tid < 128) {
        const size_t o = ((size_t)b * 8 + jb) * SEQ + i0 + tid;
        RS[o] = shrs[0][tid] + shrs[1][tid];
        if (labelp) RL[o] = shrl[0][tid] + shrl[1][tid];
    }
}

// ---------------- PV GEMM: acc = P~ x VT^T (K=SEQ); tile 64q x 128d; XCD chunk-swizzled (4,16,nb) ----------------
// mode 1: T = acc/rs + x, ssq -> SS[0][b]            (self)
// mode 2: T = acc/rs + x; mvec=(RLsum)/rs; sa=(x*m)^2 sb sab  (cross)
__global__ __launch_bounds__(256) void k_pv(const us* __restrict__ P,
                                            const us* __restrict__ VT,
                                            const us* __restrict__ XC,
                                            const float* __restrict__ RS,
                                            const float* __restrict__ RL,
                                            float* __restrict__ MVEC,
                                            float* __restrict__ Cout,
                                            float* __restrict__ SS, int b0, int mode) {
    const int flat = blockIdx.x + (int)gridDim.x * (blockIdx.y + (int)gridDim.y * blockIdx.z);
    const int chunk = ((int)gridDim.x * (int)gridDim.y * (int)gridDim.z) >> 3;
    const int logical = (flat & 7) * chunk + (flat >> 3);
    const int jx = logical & 3;
    const int iy = (logical >> 2) & 15;
    const int bz = logical >> 6;
    const int b = b0 + bz;
    const int i0 = iy * 64, j0 = jx * 128;
    const us* Pb = P + (size_t)bz * SEQ * SEQ;
    const us* Vb = VT + (size_t)b * DM * SEQ;
    __shared__ short As[64 * 64], Bs[128 * 64];
    __shared__ float sh_inv[64], sh_m[64];
    __shared__ float ps[3][4];
    const int tid = threadIdx.x, w = tid >> 6, l = tid & 63;
    const int wm = (w >> 1) * 32, wn = (w & 1) * 64;
    const int sr = l >> 3, sc = (((l & 7) ^ (l >> 3)) << 3);
    const int lr = l & 15, lk = (l >> 4) * 8;
    const int sx = (lr & 7) << 3;
    f32x4 acc[2][4] = {};
    for (int k0 = 0; k0 < SEQ; k0 += 64) {
#pragma unroll
        for (int cc = 0; cc < 2; ++cc) {
            const int c = 2 * w + cc;
            GLL16(Pb + (size_t)(i0 + c * 8 + sr) * SEQ + k0 + sc, &As[c * 512]);
        }
#pragma unroll
        for (int cc = 0; cc < 4; ++cc) {
            const int c = 4 * w + cc;
            GLL16(Vb + (size_t)(j0 + c * 8 + sr) * SEQ + k0 + sc, &Bs[c * 512]);
        }
        __syncthreads();
#pragma unroll
        for (int kc = 0; kc < 2; ++kc) {
            const int kk = kc * 32 + lk;
            bf16x8 a[2], bb[4];
#pragma unroll
            for (int fm = 0; fm < 2; ++fm)
                a[fm] = *(const bf16x8*)&As[(wm + fm * 16 + lr) * 64 + (kk ^ sx)];
#pragma unroll
            for (int fn = 0; fn < 4; ++fn)
                bb[fn] = *(const bf16x8*)&Bs[(wn + fn * 16 + lr) * 64 + (kk ^ sx)];
#pragma unroll
            for (int fm = 0; fm < 2; ++fm)
#pragma unroll
                for (int fn = 0; fn < 4; ++fn)
                    acc[fm][fn] = __builtin_amdgcn_mfma_f32_16x16x32_bf16(a[fm], bb[fn], acc[fm][fn], 0, 0, 0);
        }
        __syncthreads();
    }
    // rowsum normalization factors (+ mvec for cross)
    if (tid < 64) {
        const size_t base = (size_t)b * 8 * SEQ + i0 + tid;
        float s = 0.f;
#pragma unroll
        for (int jb = 0; jb < 8; ++jb) s += RS[base + (size_t)jb * SEQ];
        const float inv = 1.0f / s;
        sh_inv[tid] = inv;
        if (mode == 2) {
            float sl = 0.f;
#pragma unroll
            for (int jb = 0; jb < 8; ++jb) sl += RL[base + (size_t)jb * SEQ];
            const float mv = sl * inv;
            sh_m[tid] = mv;
            if (jx == 0) MVEC[(size_t)b * SEQ + i0 + tid] = mv;
        }
    }
    __syncthreads();
    const us* XCb = XC + (size_t)b * SEQ * 1024;
    float sa = 0.f, sb = 0.f, sab = 0.f;
    const int er = l & 15, eq = (l >> 4) * 4;
#pragma unroll
    for (int fm = 0; fm < 2; ++fm)
#pragma unroll
        for (int fn = 0; fn < 4; ++fn)
#pragma unroll
            for (int r = 0; r < 4; ++r) {
                const int lrow = wm + fm * 16 + eq + r;
                const int col = j0 + wn + fn * 16 + er;
                float v = acc[fm][fn][r] * sh_inv[lrow];
                const size_t o = ((size_t)b * SEQ + i0 + lrow) * DM + col;
                const size_t xo = (size_t)(i0 + lrow) * 1024 + col;
                const float x = bf2f(XCb[xo]) + bf2f(XCb[xo + 512]);
                v += x;
                sb += v * v;
                if (mode == 2) {
                    const float a = x * sh_m[lrow];
                    sa += a * a;
                    sab += a * v;
                }
                Cout[o] = v;
            }
#pragma unroll
    for (int off = 32; off > 0; off >>= 1) {
        sb += __shfl_xor(sb, off, 64);
        if (mode == 2) { sa += __shfl_xor(sa, off, 64); sab += __shfl_xor(sab, off, 64); }
    }
    if (l == 0) { ps[0][w] = sb; ps[1][w] = sa; ps[2][w] = sab; }
    __syncthreads();
    if (tid == 0) {
        if (mode == 1) {
            atomicAdd(&SS[SS_IDX(0, b)], ps[0][0] + ps[0][1] + ps[0][2] + ps[0][3]);
        } else {
            atomicAdd(&SS[SS_IDX(0, b)], ps[1][0] + ps[1][1] + ps[1][2] + ps[1][3]);
            atomicAdd(&SS[SS_IDX(1, b)], ps[0][0] + ps[0][1] + ps[0][2] + ps[0][3]);
            atomicAdd(&SS[SS_IDX(2, b)], ps[2][0] + ps[2][1] + ps[2][2] + ps[2][3]);
        }
    }
}

// ---------------- zero all SS stages ----------------
__global__ void k_zero(float* __restrict__ SSb) {
    const int i = blockIdx.x * 256 + threadIdx.x;
    if (i < SS_FLOATS) SSb[i] = 0.0f;
}

// ---------------- finish: v from T (+XC), write XC hi|lo + transposed bf16/f32 ----------------
// mode 0: v = f3*T ; mode 1: v = f3*(f1*x*mv + f2*T)  (T holds x+t3)
__global__ __launch_bounds__(256) void k_finish(const float* __restrict__ Tin,
                                                const us* __restrict__ XCin,
                                                const float* __restrict__ mv,
                                                const float* __restrict__ SS,
                                                us* __restrict__ XCout,
                                                us* __restrict__ XTb,
                                                float* __restrict__ XTf,
                                                int mode, int writeXC) {
    const int b = blockIdx.z;
    const int s0 = blockIdx.x * 32, d0 = blockIdx.y * 32;
    const int tx = threadIdx.x, ty = threadIdx.y;
    __shared__ float tile[32][33];
    float f1 = 0.f, f2 = 0.f, f3;
    if (mode == 0) {
        f3 = NS_F * sqrtf(DS_F / (SS[SS_IDX(0, b)] + 1e-5f));
    } else {
        const float ssa = SS[SS_IDX(0, b)], ssb = SS[SS_IDX(1, b)], ssab = SS[SS_IDX(2, b)];
        f1 = NS_F * sqrtf(DS_F / (ssa + 1e-5f));
        f2 = NS_F * sqrtf(DS_F / (ssb + 1e-5f));
        const float ssc = f1 * f1 * ssa + 2.f * f1 * f2 * ssab + f2 * f2 * ssb;
        f3 = NS_F * sqrtf(DS_F / (ssc + 1e-5f));
    }
#pragma unroll
    for (int j = 0; j < 4; ++j) {
        const int s = s0 + ty + j * 8;
        const int d = d0 + tx;
        const size_t o = ((size_t)b * SEQ + s) * DM + d;
        const size_t xo = ((size_t)b * SEQ + s) * 1024 + d;
        float v;
        if (mode == 0) v = f3 * Tin[o];
        else {
            const float x = bf2f(XCin[xo]) + bf2f(XCin[xo + 512]);
            v = f3 * (f1 * x * mv[(size_t)b * SEQ + s] + f2 * Tin[o]);
        }
        if (writeXC) {
            const us h = f2bf(v);
            XCout[xo] = h;
            XCout[xo + 512] = f2bf(v - bf2f(h));
        }
        tile[ty + j * 8][tx] = v;
    }
    __syncthreads();
#pragma unroll
    for (int j = 0; j < 4; ++j) {
        const int d = d0 + ty + j * 8;
        const int s = s0 + tx;
        const float v = tile[tx][ty + j * 8];
        const size_t o = ((size_t)b * DM + d) * SEQ + s;
        if (XTb) XTb[o] = f2bf(v);
        else if (XTf) XTf[o] = v;
    }
}

extern "C" void kernel_launch(void* const* d_in, const int* in_sizes, int n_in,
                              void* d_out, int out_size, void* d_ws, size_t ws_size,
                              hipStream_t stream) {
    const float* train_feat = (const float*)d_in[0];
    const float* test_feat  = (const float*)d_in[1];
    const float* label      = (const float*)d_in[2];
    const float* WKs        = (const float*)d_in[3];
    const float* bKs        = (const float*)d_in[4];
    const float* WKc        = (const float*)d_in[5];
    const float* bKc        = (const float*)d_in[6];
    float* out = (float*)d_out;
    float* w = (float*)d_ws;

    const size_t SBD = (size_t)NB * SEQ * DM;   // 8,388,608 elems
    const size_t SBK = (size_t)NB * SEQ * KD;

    float* T   = w;                                  // SBD f32
    us* XC     = (us*)(T + SBD);                     // 2*SBD us (hi|lo)
    us* XTd    = XC + 2 * SBD;                       // SBD us
    us* MEMT   = XTd + SBD;                          // SBD us
    us* MEMLT  = MEMT + SBD;                         // SBD us
    us* W1C    = MEMLT + SBD;                        // 2*SBK us
    us* WKMC   = W1C + 2 * SBK;                      // 2*SBK us
    us* WCs    = WKMC + 2 * SBK;                     // KD*1024 us
    us* WCc    = WCs + (size_t)KD * 1024;
    float* MVEC = (float*)(WCc + (size_t)KD * 1024); // NB*SEQ f32
    float* SS   = MVEC + (size_t)NB * SEQ;           // SS_FLOATS
    float* RS   = SS + SS_FLOATS;                    // NB*8*SEQ f32
    float* RL   = RS + (size_t)NB * 8 * SEQ;         // NB*8*SEQ f32
    float* Pf   = RL + (size_t)NB * 8 * SEQ;         // cap*SEQ*SEQ/2 f32-equiv (P bf16)

    const size_t fixed = (size_t)(Pf - w);
    const size_t per = (size_t)SEQ * SEQ / 2;  // P bf16 per batch, in f32 units
    const size_t wsf = ws_size / 4;
    int cap = 1;
    if (wsf > fixed) {
        size_t c = (wsf - fixed) / per;
        if (c < 1) c = 1;
        if (c > NB) c = NB;
        cap = (int)c;
    }
    us* Pbuf = (us*)Pf;

    const dim3 gT_in(DM / 32, SEQ / 32, NB), bT(32, 8);
    const dim3 gFin(SEQ / 32, DM / 32, NB);

    int stage = 0;
    auto nextSS = [&]() { return SS + (size_t)(stage++) * SS_STRIDE; };

    auto attn = [&](const us* Qc, const us* Kc, const us* VT,
                    const float* labelp, int pvmode, float* SSst) {
        for (int b0 = 0; b0 < NB; b0 += cap) {
            const int nb = (NB - b0 < cap) ? NB - b0 : cap;
            k_qk<<<dim3(8, 8, nb), 256, 0, stream>>>(Qc, Kc, labelp, Pbuf, RS, RL, b0);
            k_pv<<<dim3(4, 16, nb), 256, 0, stream>>>(Pbuf, VT, XC, RS, RL, MVEC, T, SSst, b0, pvmode);
        }
    };

    // ---------------- setup ----------------
    k_zero<<<(SS_FLOATS + 255) / 256, 256, 0, stream>>>(SS);
    k_wsplit<<<KD, 256, 0, stream>>>(WKs, WCs);
    k_wsplit<<<KD, 256, 0, stream>>>(WKc, WCc);

    // ---------------- encoder ----------------
    k_transpose_in<<<gT_in, bT, 0, stream>>>(train_feat, XC, MEMT);
    for (int l = 0; l < 2; ++l) {
        float* SSst = nextSS();
        k_proj<<<NB * SEQ / 32, 256, 0, stream>>>(XC, WCs, bKs, W1C);
        attn(W1C, W1C, MEMT, nullptr, 1, SSst);
        k_finish<<<gFin, bT, 0, stream>>>(T, XC, nullptr, SSst, XC, MEMT, nullptr, 0, 1);
    }
    k_proj<<<NB * SEQ / 32, 256, 0, stream>>>(XC, WCc, bKc, WKMC);
    k_mklabel<<<dim3(DM * SEQ / 8 / 256, NB), 256, 0, stream>>>(MEMT, label, MEMLT);

    // ---------------- decoder (x2) ----------------
    auto decoder = [&](const float* feat, float* outp) {
        k_transpose_in<<<gT_in, bT, 0, stream>>>(feat, XC, XTd);
        for (int l = 0; l < 2; ++l) {
            // self-attn + inorm
            float* SSst = nextSS();
            k_proj<<<NB * SEQ / 32, 256, 0, stream>>>(XC, WCs, bKs, W1C);
            attn(W1C, W1C, XTd, nullptr, 1, SSst);
            k_finish<<<gFin, bT, 0, stream>>>(T, XC, nullptr, SSst, XC, XTd, nullptr, 0, 1);
            // cross-attn (fused reduce3): T = x + t3; SS = ssa/ssb/ssab; MVEC = mask
            float* SSst2 = nextSS();
            k_proj<<<NB * SEQ / 32, 256, 0, stream>>>(XC, WCc, bKc, W1C);
            attn(W1C, WKMC, MEMLT, label, 2, SSst2);
            // fused triple instance-norm finish
            if (l == 0)
                k_finish<<<gFin, bT, 0, stream>>>(T, XC, MVEC, SSst2, XC, XTd, nullptr, 1, 1);
            else
                k_finish<<<gFin, bT, 0, stream>>>(T, XC, MVEC, SSst2, XC, nullptr, outp, 1, 0);
        }
    };
    decoder(train_feat, out);
    decoder(test_feat, out + SBD);
}